// Round 2
// baseline (288.397 us; speedup 1.0000x reference)
//
#include <hip/hip_runtime.h>
#include <hip/hip_fp16.h>

// ---------------------------------------------------------------------------
// GAT 2-layer forward. N=50000 nodes, F=128, E=1.6M random edges (+N implicit
// self loops). L1: H=2,C=64 concat -> relu. L2: H=1,C=16.
//
// Dispatches: memset -> {partition || gemm1} -> bucket_build -> agg1b
// (bucket-staged, head-split) -> combine -> agg2.
//
// R14: head-split (head=blockIdx&1 -> XCD parity) cut agg1 FETCH 157->109MB
// but dur stayed 65->68us: NOT BW-bound. hbm_gbps fell 2.5->1.7TB/s at
// constant time => latency-bound: 5 dependent global latencies per wave
// (nodeseg->csr->asrc->exp->gather) amortized over only ~2 gather iters.
//
// R15 (this): bucket-staged agg1. Block = (bucket-quarter, head): stages
// (src<<8, alpha_src) for a contiguous 32-node CSR slice into LDS once
// (coalesced csr, 6-deep pipelined alpha gathers), plus per-node meta
// (seg, adst, asrc). Per-node setup = LDS-only; xw gathers issued up to
// 8-deep per lane (whole <=64-edge chunk in flight, exp weights computed
// from LDS while loads fly). w2/b1 hoisted to registers per wave. ~105
// VGPR -> 4 waves/SIMD; ILP replaces TLP.
//
// gemm1: fp16 MFMA (mfma_f32_16x16x32_f16), LDS stride-136 fp16, fp32
// accumulate, epilogue stages C through LDS for coalesced fp16 stores +
// fused layer-1 logits. Softmax without max-shift (logits bounded, fp32 exp
// safe; ratio identical to reference in exact math). xw stored fp16.
// ---------------------------------------------------------------------------

#define BSHIFT 7                 // 128 dst nodes per bucket
#define MAXB 512                 // supports N <= 65536
#define CAPMAX 6144              // LDS edge-staging bound (entries)
#define XS 136
#define STGQ 1536                // staged edges per 32-node quarter (mean
                                 // 1024, +16sigma; global fallback beyond)
#define QSH 5                    // 32 nodes per agg1b block

using f16x8 = __attribute__((ext_vector_type(8))) _Float16;
using f16x4 = __attribute__((ext_vector_type(4))) _Float16;
using f32x4 = __attribute__((ext_vector_type(4))) float;

__device__ __forceinline__ float lrelu(float a) { return fmaxf(a, 0.2f * a); }

// ---------------- fused: partition (blocks 0..NB-1) + gemm1 (rest) --------

__global__ __launch_bounds__(256) void part_gemm1_kernel(
    const int* __restrict__ src, const int* __restrict__ dst,
    int* __restrict__ bincur, unsigned* __restrict__ binned,
    int E, int B, int CH, int CAP, int NB,
    const float* __restrict__ x, const float* __restrict__ w1,
    const float* __restrict__ as1, const float* __restrict__ ad1,
    __half* __restrict__ xw1h, float* __restrict__ asrc1,
    float* __restrict__ adst1, int N) {
  __shared__ __align__(16) char smem[(64 + 128) * XS * 2];  // 52224 B
  int t = threadIdx.x;

  if (blockIdx.x < (unsigned)NB) {
    // ---- partition: single global pass; pack edges into LDS ----
    int* s_h = (int*)smem;
    int* s_base = s_h + MAXB;
    int* s_cur = s_base + MAXB;
    unsigned* s_pack = (unsigned*)(s_cur + MAXB);  // CH <= 6250 -> 25 KB
    for (int i = t; i < B; i += 256) s_h[i] = 0;
    __syncthreads();
    int lo = blockIdx.x * CH;
    int cnt = min(CH, E - lo);
    for (int i = t; i < cnt; i += 256) {
      int d = dst[lo + i];
      int s = src[lo + i];
      atomicAdd(&s_h[d >> BSHIFT], 1);
      s_pack[i] = (unsigned)s | ((unsigned)(d & 127) << 16) |
                  ((unsigned)(d >> BSHIFT) << 23);
    }
    __syncthreads();
    for (int i = t; i < B; i += 256) {
      int c = s_h[i];
      s_base[i] = c ? (i * CAP + atomicAdd(&bincur[i], c)) : 0;
      s_cur[i] = 0;
    }
    __syncthreads();
    for (int i = t; i < cnt; i += 256) {
      unsigned e = s_pack[i];
      int b = e >> 23;
      int r = atomicAdd(&s_cur[b], 1);
      binned[s_base[b] + r] = e & 0x7FFFFFu;
    }
    return;
  }

  // ---- gemm1: 64-node tile, fp16 MFMA, fused logits ----
  _Float16* lx = (_Float16*)smem;
  _Float16* lw = lx + 64 * XS;
  int n0 = (blockIdx.x - NB) * 64;

#pragma unroll
  for (int j = 0; j < 8; ++j) {
    int idx = t + 256 * j;
    int nd = idx >> 5, i4 = (idx & 31) * 4;
    int gn = n0 + nd;
    float4 v = (gn < N) ? *(const float4*)&x[(size_t)gn * 128 + i4]
                        : make_float4(0.f, 0.f, 0.f, 0.f);
    f16x4 h;
    h[0] = (_Float16)v.x; h[1] = (_Float16)v.y;
    h[2] = (_Float16)v.z; h[3] = (_Float16)v.w;
    *(f16x4*)&lx[nd * XS + i4] = h;
  }
#pragma unroll
  for (int j = 0; j < 16; ++j) {
    int idx = t + 256 * j;
    int o = idx >> 5, i4 = (idx & 31) * 4;
    float4 v = *(const float4*)&w1[(size_t)o * 128 + i4];
    f16x4 h;
    h[0] = (_Float16)v.x; h[1] = (_Float16)v.y;
    h[2] = (_Float16)v.z; h[3] = (_Float16)v.w;
    *(f16x4*)&lw[o * XS + i4] = h;
  }
  __syncthreads();

  int lane = t & 63, wv = t >> 6;
  int m16 = lane & 15, q = lane >> 4;

  f32x4 acc[8];
#pragma unroll
  for (int i = 0; i < 8; ++i) acc[i] = (f32x4){0.f, 0.f, 0.f, 0.f};

#pragma unroll
  for (int c = 0; c < 4; ++c) {
    f16x8 a = *(const f16x8*)&lx[(16 * wv + m16) * XS + c * 32 + q * 8];
#pragma unroll
    for (int tt = 0; tt < 8; ++tt) {
      f16x8 b = *(const f16x8*)&lw[(tt * 16 + m16) * XS + c * 32 + q * 8];
      acc[tt] = __builtin_amdgcn_mfma_f32_16x16x32_f16(a, b, acc[tt], 0, 0, 0);
    }
  }

  // write C to this wave's own lx rows (wave-private; no barrier needed)
#pragma unroll
  for (int tt = 0; tt < 8; ++tt) {
#pragma unroll
    for (int r = 0; r < 4; ++r) {
      lx[(16 * wv + 4 * q + r) * XS + tt * 16 + m16] = (_Float16)acc[tt][r];
    }
  }

  // logits: lane -> node m16, o-part p = q (32 outputs each)
  {
    float ps = 0.f, pd = 0.f;
    int p = q;
#pragma unroll
    for (int k = 0; k < 4; ++k) {
      f16x8 hv = *(const f16x8*)&lx[(16 * wv + m16) * XS + p * 32 + k * 8];
      float4 s0 = *(const float4*)&as1[p * 32 + k * 8];
      float4 s1 = *(const float4*)&as1[p * 32 + k * 8 + 4];
      float4 d0 = *(const float4*)&ad1[p * 32 + k * 8];
      float4 d1 = *(const float4*)&ad1[p * 32 + k * 8 + 4];
      ps += (float)hv[0] * s0.x + (float)hv[1] * s0.y + (float)hv[2] * s0.z +
            (float)hv[3] * s0.w + (float)hv[4] * s1.x + (float)hv[5] * s1.y +
            (float)hv[6] * s1.z + (float)hv[7] * s1.w;
      pd += (float)hv[0] * d0.x + (float)hv[1] * d0.y + (float)hv[2] * d0.z +
            (float)hv[3] * d0.w + (float)hv[4] * d1.x + (float)hv[5] * d1.y +
            (float)hv[6] * d1.z + (float)hv[7] * d1.w;
    }
    ps += __shfl_xor(ps, 16);
    pd += __shfl_xor(pd, 16);
    int n = n0 + 16 * wv + m16;
    if (n < N && (q == 0 || q == 2)) {
      int hh = q >> 1;
      asrc1[2 * n + hh] = ps;
      adst1[2 * n + hh] = pd;
    }
  }

  // coalesced fp16 stores: 16 rows x 16 uint4 per wave -> 4 per lane
#pragma unroll
  for (int i = 0; i < 4; ++i) {
    int m = q + 4 * i;
    int n = n0 + 16 * wv + m;
    if (n < N) {
      uint4 v = *(const uint4*)&lx[(16 * wv + m) * XS + m16 * 8];
      *(uint4*)&xw1h[(size_t)n * 128 + m16 * 8] = v;
    }
  }
}

// ---------------- bucket_build: all-LDS, staged edges, ushort csr ---------

__global__ __launch_bounds__(256) void bucket_build_kernel(const unsigned* __restrict__ binned,
                                                           const int* __restrict__ bincur,
                                                           int2* __restrict__ nodeseg,
                                                           unsigned short* __restrict__ csr,
                                                           int N, int CAP) {
  __shared__ int s_deg[128];
  __shared__ int s_cur[128];
  __shared__ int s_wsum;
  __shared__ unsigned s_edges[CAPMAX];
  int b = blockIdx.x;
  int lo = b * CAP, hi = lo + bincur[b];
  int cnt = hi - lo;
  int t = threadIdx.x;
  if (t < 128) s_deg[t] = 0;
  int stg = min(cnt, CAPMAX);
  for (int i = t; i < stg; i += 256) s_edges[i] = binned[lo + i];
  __syncthreads();
  for (int i = t; i < cnt; i += 256) {
    unsigned e = (i < CAPMAX) ? s_edges[i] : binned[lo + i];
    atomicAdd(&s_deg[e >> 16], 1);
  }
  __syncthreads();
  int lane = t & 63, wv = t >> 6;
  int v = (t < 128) ? s_deg[t] : 0;
  int incl = v;
#pragma unroll
  for (int off = 1; off < 64; off <<= 1) {
    int u = __shfl_up(incl, off);
    if (lane >= off) incl += u;
  }
  if (t == 63) s_wsum = incl;  // wave-0 total
  __syncthreads();
  int excl = incl - v + ((wv == 1) ? s_wsum : 0);
  if (t < 128) {
    int node = (b << BSHIFT) + t;
    if (node < N) nodeseg[node] = make_int2(lo + excl, lo + excl + v);
    s_cur[t] = lo + excl;
  }
  __syncthreads();
  for (int i = t; i < cnt; i += 256) {
    unsigned e = (i < CAPMAX) ? s_edges[i] : binned[lo + i];
    int p = atomicAdd(&s_cur[e >> 16], 1);  // LDS atomic
    csr[p] = (unsigned short)(e & 0xFFFFu);
  }
}

// ---------------- agg1b: bucket-staged aggregation + partial gemm2 --------

// Block = (bucket-quarter, head). head = blockIdx&1 -> XCD parity (measured
// R14: fetch 157->109MB). Stage phase: coalesced csr + pipelined alpha
// gathers -> LDS (src<<8, alpha_src) for the contiguous 32-node CSR slice;
// node meta (seg/adst/asrc) staged too. Agg phase: wave per node, 8 rows x
// 8 c8 lanes; whole <=64-edge chunk issued (8 uint4 in flight per lane),
// exp weights computed from LDS while loads fly. w2/b1 hoisted per wave.
__global__ __launch_bounds__(256) void agg1b_kernel(const __half* __restrict__ xw1h,
                                                    const float* __restrict__ asrc1,
                                                    const float* __restrict__ adst1,
                                                    const float* __restrict__ b1,
                                                    const float* __restrict__ w2,
                                                    const unsigned short* __restrict__ csr,
                                                    const int2* __restrict__ nodeseg,
                                                    float* __restrict__ p_out, int N) {
  __shared__ int s_off[STGQ];    // src byte offset (src*256)
  __shared__ float s_al[STGQ];   // alpha_src for this head
  __shared__ int2 s_seg[32];     // block-local edge segment per node
  __shared__ float s_ad[32];
  __shared__ float s_as[32];

  int t = threadIdx.x;
  int head = blockIdx.x & 1;
  int quarter = (blockIdx.x >> 1) & 3;
  int bucket = blockIdx.x >> 3;
  int n0 = (bucket << BSHIFT) + (quarter << QSH);
  int nCnt = min(32, N - n0);
  if (nCnt <= 0) return;

  int lo = nodeseg[n0].x;
  int hi = nodeseg[n0 + nCnt - 1].y;
  int cnt = hi - lo;

  if (t < nCnt) {
    int2 sg = nodeseg[n0 + t];
    s_seg[t] = make_int2(sg.x - lo, sg.y - lo);
    s_ad[t] = adst1[2 * (n0 + t) + head];
    s_as[t] = asrc1[2 * (n0 + t) + head];
  }
#pragma unroll
  for (int kk = 0; kk < STGQ / 256; ++kk) {
    int i = t + 256 * kk;
    if (i < cnt) {
      int s = (int)csr[lo + i];
      s_off[i] = s << 8;
      s_al[i] = asrc1[2 * s + head];
    }
  }
  __syncthreads();

  int lane = t & 63, wv = t >> 6;
  int c8 = lane & 7;   // head-local channels 8*c8 .. 8*c8+7
  int row = lane >> 3; // 0..7 edge subgroup
  const char* xb = (const char*)xw1h + (head << 7) + 16 * c8;

  // hoisted per-lane constants (w2 slice: output rows 2*row, 2*row+1)
  int cb = head * 64 + 8 * c8;
  float4 blo = *(const float4*)&b1[cb];
  float4 bhi = *(const float4*)&b1[cb + 4];
  float4 w0lo = *(const float4*)&w2[(size_t)(2 * row) * 128 + cb];
  float4 w0hi = *(const float4*)&w2[(size_t)(2 * row) * 128 + cb + 4];
  float4 w1lo = *(const float4*)&w2[(size_t)(2 * row + 1) * 128 + cb];
  float4 w1hi = *(const float4*)&w2[(size_t)(2 * row + 1) * 128 + cb + 4];

  for (int nl = wv; nl < nCnt; nl += 4) {
    int d = n0 + nl;
    int2 sg = s_seg[nl];
    float adv = s_ad[nl];
    float wself = __expf(lrelu(s_as[nl] + adv));

    float a[8];
    float sum = 0.f;
#pragma unroll
    for (int k = 0; k < 8; ++k) a[k] = 0.f;
    if (row == 0) {  // self edge handled once, by row 0
      uint4 r = *(const uint4*)(xb + ((size_t)d << 8));
      const __half2* hp = (const __half2*)&r;
#pragma unroll
      for (int k = 0; k < 4; ++k) {
        float2 v = __half22float2(hp[k]);
        a[2 * k] = wself * v.x;
        a[2 * k + 1] = wself * v.y;
      }
      sum = wself;
    }

    for (int base = sg.x; base < sg.y; base += 64) {
      int take = sg.y - base;
      if (take > 64) take = 64;
      uint4 rr[8];
      float wgt[8];
#pragma unroll
      for (int k = 0; k < 8; ++k) {
        int e = row + 8 * k;
        if (e < take) {
          int idx = base + e;
          int off;
          float al;
          if (idx < STGQ) {
            off = s_off[idx];
            al = s_al[idx];
          } else {  // statistical overflow fallback (never in practice)
            int s = (int)csr[lo + idx];
            off = s << 8;
            al = asrc1[2 * s + head];
          }
          rr[k] = *(const uint4*)(xb + off);
          wgt[k] = __expf(lrelu(al + adv));
        }
      }
#pragma unroll
      for (int k = 0; k < 8; ++k) {
        int e = row + 8 * k;
        if (e < take) {
          const __half2* hp = (const __half2*)&rr[k];
          float w = wgt[k];
#pragma unroll
          for (int q2 = 0; q2 < 4; ++q2) {
            float2 v = __half22float2(hp[q2]);
            a[2 * q2] += w * v.x;
            a[2 * q2 + 1] += w * v.y;
          }
          sum += w;
        }
      }
    }

    // butterfly across the 8 rows -> every lane holds full sums for its c8
#pragma unroll
    for (int k = 0; k < 8; ++k) {
      a[k] += __shfl_xor(a[k], 8);
      a[k] += __shfl_xor(a[k], 16);
      a[k] += __shfl_xor(a[k], 32);
    }
    sum += __shfl_xor(sum, 8);
    sum += __shfl_xor(sum, 16);
    sum += __shfl_xor(sum, 32);

    // h (relu'd, biased) in registers — every lane holds 8 head-local chans
    float inv = 1.f / (sum + 1e-16f);
    float h[8];
    h[0] = fmaxf(a[0] * inv + blo.x, 0.f);
    h[1] = fmaxf(a[1] * inv + blo.y, 0.f);
    h[2] = fmaxf(a[2] * inv + blo.z, 0.f);
    h[3] = fmaxf(a[3] * inv + blo.w, 0.f);
    h[4] = fmaxf(a[4] * inv + bhi.x, 0.f);
    h[5] = fmaxf(a[5] * inv + bhi.y, 0.f);
    h[6] = fmaxf(a[6] * inv + bhi.z, 0.f);
    h[7] = fmaxf(a[7] * inv + bhi.w, 0.f);

    // partial gemm2 over this head's 64 channels: row r -> channels 2r,2r+1
    float p0 = h[0] * w0lo.x + h[1] * w0lo.y + h[2] * w0lo.z + h[3] * w0lo.w +
               h[4] * w0hi.x + h[5] * w0hi.y + h[6] * w0hi.z + h[7] * w0hi.w;
    float p1 = h[0] * w1lo.x + h[1] * w1lo.y + h[2] * w1lo.z + h[3] * w1lo.w +
               h[4] * w1hi.x + h[5] * w1hi.y + h[6] * w1hi.z + h[7] * w1hi.w;
#pragma unroll
    for (int k = 1; k < 8; k <<= 1) {
      p0 += __shfl_xor(p0, k);
      p1 += __shfl_xor(p1, k);
    }
    if (c8 == 0) {  // one lane per row stores its 2 partial channels (8B)
      *(float2*)&p_out[(size_t)d * 32 + head * 16 + 2 * row] =
          make_float2(p0, p1);
    }
  }
}

// ---------------- combine: xw2 = p0 + p1, fp16 store + layer-2 logits -----

__global__ __launch_bounds__(256) void combine_kernel(const float* __restrict__ p,
                                                      const float* __restrict__ as2,
                                                      const float* __restrict__ ad2,
                                                      __half* __restrict__ xw2h,
                                                      float* __restrict__ asrc2,
                                                      float* __restrict__ adst2, int N) {
  int idx = blockIdx.x * 256 + threadIdx.x;
  int node = idx >> 4, c = idx & 15;
  if (node >= N) return;
  float v = p[(size_t)node * 32 + c] + p[(size_t)node * 32 + 16 + c];
  xw2h[(size_t)node * 16 + c] = __float2half(v);
  float qs = v * as2[c], qd = v * ad2[c];
#pragma unroll
  for (int k = 1; k < 16; k <<= 1) {
    qs += __shfl_xor(qs, k);
    qd += __shfl_xor(qd, k);
  }
  if (c == 0) {
    asrc2[node] = qs;
    adst2[node] = qd;
  }
}

// ---------------- agg2 ----------------

// wave per dst node. 8 rows x 8 lanes x 4B; 16-edge unroll = 2 loads in
// flight. Each lane owns 2 channels (half2).
__global__ __launch_bounds__(256) void agg2_kernel(const __half* __restrict__ xw2h,
                                                   const float* __restrict__ asrc2,
                                                   const float* __restrict__ adst2,
                                                   const float* __restrict__ b2,
                                                   const unsigned short* __restrict__ csr,
                                                   const int2* __restrict__ nodeseg,
                                                   float* __restrict__ out, int N) {
  __shared__ int s_off[4][64];   // row byte offset (s * 32)
  __shared__ float s_w[4][64];
  int lane = threadIdx.x & 63, wv = threadIdx.x >> 6;
  int d = blockIdx.x * 4 + wv;
  if (d >= N) return;
  int c2 = lane & 7;   // channels 2*c2, 2*c2+1
  int row = lane >> 3; // 0..7
  int2 seg = nodeseg[d];
  int e0 = seg.x, e1 = seg.y;
  float advd = adst2[d];
  float wself = __expf(lrelu(asrc2[d] + advd));
  const char* xb = (const char*)xw2h + 4 * c2;

  float a0 = 0.f, a1 = 0.f, sum = 0.f;
  if (row == 0) {
    float2 v = __half22float2(*(const __half2*)(xb + (size_t)d * 32));
    a0 = wself * v.x;
    a1 = wself * v.y;
    sum = wself;
  }
  for (int base = e0; base < e1; base += 64) {
    int cnt = min(64, e1 - base);
    if (lane < cnt) {
      int s = (int)csr[base + lane];
      s_off[wv][lane] = s << 5;
      s_w[wv][lane] = __expf(lrelu(asrc2[s] + advd));
    }
    int j = 0;
    for (; j + 15 < cnt; j += 16) {
      int o0 = s_off[wv][j + row];
      int o1 = s_off[wv][j + 8 + row];
      float w0 = s_w[wv][j + row];
      float w1 = s_w[wv][j + 8 + row];
      float2 v0 = __half22float2(*(const __half2*)(xb + o0));
      float2 v1 = __half22float2(*(const __half2*)(xb + o1));
      a0 += w0 * v0.x + w1 * v1.x;
      a1 += w0 * v0.y + w1 * v1.y;
      sum += w0 + w1;
    }
    for (; j + 7 < cnt; j += 8) {
      int o0 = s_off[wv][j + row];
      float w0 = s_w[wv][j + row];
      float2 v0 = __half22float2(*(const __half2*)(xb + o0));
      a0 += w0 * v0.x;
      a1 += w0 * v0.y;
      sum += w0;
    }
    if (row < cnt - j) {  // tail: rows 0..cnt-j-1 take one edge each
      int o0 = s_off[wv][j + row];
      float w0 = s_w[wv][j + row];
      float2 v0 = __half22float2(*(const __half2*)(xb + o0));
      a0 += w0 * v0.x;
      a1 += w0 * v0.y;
      sum += w0;
    }
  }
#pragma unroll
  for (int k = 8; k < 64; k <<= 1) {
    a0 += __shfl_xor(a0, k);
    a1 += __shfl_xor(a1, k);
    sum += __shfl_xor(sum, k);
  }
  if (lane < 8) {
    float inv = 1.f / (sum + 1e-16f);
    float2 r;
    r.x = a0 * inv + b2[2 * c2];
    r.y = a1 * inv + b2[2 * c2 + 1];
    *(float2*)&out[(size_t)d * 16 + 2 * c2] = r;
  }
}

// ---------------------------------------------------------------------------

extern "C" void kernel_launch(void* const* d_in, const int* in_sizes, int n_in,
                              void* d_out, int out_size, void* d_ws, size_t ws_size,
                              hipStream_t stream) {
  const float* x = (const float*)d_in[0];
  const int* ei = (const int*)d_in[1];
  const float* w1 = (const float*)d_in[2];
  const float* as1 = (const float*)d_in[3];
  const float* ad1 = (const float*)d_in[4];
  const float* b1 = (const float*)d_in[5];
  const float* w2 = (const float*)d_in[6];
  const float* as2 = (const float*)d_in[7];
  const float* ad2 = (const float*)d_in[8];
  const float* b2 = (const float*)d_in[9];
  float* out = (float*)d_out;

  int N = in_sizes[0] / 128;
  int E = in_sizes[1] / 2;
  const int* srcp = ei;
  const int* dstp = ei + E;

  int B = (N + (1 << BSHIFT) - 1) >> BSHIFT;  // 391 buckets (N<=65536 req'd)
  // bucket capacity: mean + 25% slack (+512), rounded to 256 (Poisson ~16sig)
  int mean = (E + B - 1) / B;
  int CAP = (mean + mean / 4 + 512 + 255) & ~255;
  const int NB = 256;  // partition blocks
  int CH = (E + NB - 1) / NB;  // 6250 -> 25 KB LDS packing buffer
  int GB = (N + 63) / 64;  // gemm1 tiles

  char* p = (char*)d_ws;
  auto alloc = [&](size_t bytes) -> void* {
    void* r = (void*)p;
    p += (bytes + 255) & ~(size_t)255;
    return r;
  };
  __half* xw1h = (__half*)alloc((size_t)N * 128 * 2);
  float* asrc1 = (float*)alloc((size_t)N * 2 * 4);
  float* adst1 = (float*)alloc((size_t)N * 2 * 4);
  __half* xw2h = (__half*)alloc((size_t)N * 16 * 2);
  float* asrc2 = (float*)alloc((size_t)N * 4);
  float* adst2 = (float*)alloc((size_t)N * 4);
  float* p_out = (float*)alloc((size_t)N * 32 * 4);  // [N][head][16] fp32
  int2* nodeseg = (int2*)alloc((size_t)N * 8);
  unsigned short* csr = (unsigned short*)alloc((size_t)B * CAP * 2);
  unsigned* binned = (unsigned*)alloc((size_t)B * CAP * 4);
  int* bincur = (int*)alloc((size_t)B * 4);

  hipMemsetAsync(bincur, 0, (size_t)B * 4, stream);
  part_gemm1_kernel<<<NB + GB, 256, 0, stream>>>(srcp, dstp, bincur, binned,
                                                 E, B, CH, CAP, NB,
                                                 x, w1, as1, ad1, xw1h, asrc1, adst1, N);
  bucket_build_kernel<<<B, 256, 0, stream>>>(binned, bincur, nodeseg, csr, N, CAP);
  agg1b_kernel<<<8 * B, 256, 0, stream>>>(xw1h, asrc1, adst1, b1, w2,
                                          csr, nodeseg, p_out, N);
  combine_kernel<<<(N * 16 + 255) / 256, 256, 0, stream>>>(p_out, as2, ad2,
                                                           xw2h, asrc2, adst2, N);
  agg2_kernel<<<(N + 3) / 4, 256, 0, stream>>>(xw2h, asrc2, adst2, b2, csr, nodeseg, out, N);
}

// Round 3
// 225.967 us; speedup vs baseline: 1.2763x; 1.2763x over previous
//
#include <hip/hip_runtime.h>
#include <hip/hip_fp16.h>

// ---------------------------------------------------------------------------
// GAT 2-layer forward. N=50000 nodes, F=128, E=1.6M random edges (+N implicit
// self loops). L1: H=2,C=64 concat -> relu. L2: H=1,C=16.
//
// Dispatches: memset -> {partition || gemm1} -> bucket_build -> agg1h
// (head-split) -> combine -> wprep2 -> agg2.
//
// R14: head-split (head=blockIdx&1 -> XCD parity) cut agg1 FETCH 157->109MB;
// dur flat => agg1h sits on a ~6.6TB/s device-wide vector-request wall
// (R0: 435MB req/65us = 6.7 TB/s; R1: 448MB/68us = 6.6 TB/s, invariant
// across miss-fraction change). Requests are irreducible => 68us is agg1h's
// structural floor. R15 (bucket-staged agg1) regressed 2.1x: TLP collapse
// (occ 72->27%) outweighed chain amortization — reverted.
//
// R16 (this): agg2 is the suspect for the unaccounted ~60us: its table is
// 1.6MB (L2-resident everywhere, ~no misses, ~10us of requests) => if slow,
// it's latency-CHAIN bound (1 node/wave, deg~33 = single chunk, 5 serial
// latencies, gathers only 2 deep). Fix: (a) wprep2 streaming kernel
// precomputes per-edge exp(lrelu(asrc2[s]+adst2[d])) into a CSR-aligned
// plane (bucket_build now also records dst-local per csr slot, 1B/edge);
// (b) agg2 staging = two coalesced reads; row gathers issued 8-deep in one
// shot per chunk. agg1h untouched.
//
// gemm1: fp16 MFMA (mfma_f32_16x16x32_f16), LDS stride-136 fp16, fp32
// accumulate, epilogue stages C through LDS for coalesced fp16 stores +
// fused layer-1 logits. Softmax without max-shift (logits bounded, fp32 exp
// safe; ratio identical to reference in exact math). xw stored fp16.
// ---------------------------------------------------------------------------

#define BSHIFT 7                 // 128 dst nodes per bucket
#define MAXB 512                 // supports N <= 65536
#define CAPMAX 6144              // LDS edge-staging bound (entries)
#define XS 136

using f16x8 = __attribute__((ext_vector_type(8))) _Float16;
using f16x4 = __attribute__((ext_vector_type(4))) _Float16;
using f32x4 = __attribute__((ext_vector_type(4))) float;

__device__ __forceinline__ float lrelu(float a) { return fmaxf(a, 0.2f * a); }

// ---------------- fused: partition (blocks 0..NB-1) + gemm1 (rest) --------

__global__ __launch_bounds__(256) void part_gemm1_kernel(
    const int* __restrict__ src, const int* __restrict__ dst,
    int* __restrict__ bincur, unsigned* __restrict__ binned,
    int E, int B, int CH, int CAP, int NB,
    const float* __restrict__ x, const float* __restrict__ w1,
    const float* __restrict__ as1, const float* __restrict__ ad1,
    __half* __restrict__ xw1h, float* __restrict__ asrc1,
    float* __restrict__ adst1, int N) {
  __shared__ __align__(16) char smem[(64 + 128) * XS * 2];  // 52224 B
  int t = threadIdx.x;

  if (blockIdx.x < (unsigned)NB) {
    // ---- partition: single global pass; pack edges into LDS ----
    int* s_h = (int*)smem;
    int* s_base = s_h + MAXB;
    int* s_cur = s_base + MAXB;
    unsigned* s_pack = (unsigned*)(s_cur + MAXB);  // CH <= 6250 -> 25 KB
    for (int i = t; i < B; i += 256) s_h[i] = 0;
    __syncthreads();
    int lo = blockIdx.x * CH;
    int cnt = min(CH, E - lo);
    for (int i = t; i < cnt; i += 256) {
      int d = dst[lo + i];
      int s = src[lo + i];
      atomicAdd(&s_h[d >> BSHIFT], 1);
      s_pack[i] = (unsigned)s | ((unsigned)(d & 127) << 16) |
                  ((unsigned)(d >> BSHIFT) << 23);
    }
    __syncthreads();
    for (int i = t; i < B; i += 256) {
      int c = s_h[i];
      s_base[i] = c ? (i * CAP + atomicAdd(&bincur[i], c)) : 0;
      s_cur[i] = 0;
    }
    __syncthreads();
    for (int i = t; i < cnt; i += 256) {
      unsigned e = s_pack[i];
      int b = e >> 23;
      int r = atomicAdd(&s_cur[b], 1);
      binned[s_base[b] + r] = e & 0x7FFFFFu;
    }
    return;
  }

  // ---- gemm1: 64-node tile, fp16 MFMA, fused logits ----
  _Float16* lx = (_Float16*)smem;
  _Float16* lw = lx + 64 * XS;
  int n0 = (blockIdx.x - NB) * 64;

#pragma unroll
  for (int j = 0; j < 8; ++j) {
    int idx = t + 256 * j;
    int nd = idx >> 5, i4 = (idx & 31) * 4;
    int gn = n0 + nd;
    float4 v = (gn < N) ? *(const float4*)&x[(size_t)gn * 128 + i4]
                        : make_float4(0.f, 0.f, 0.f, 0.f);
    f16x4 h;
    h[0] = (_Float16)v.x; h[1] = (_Float16)v.y;
    h[2] = (_Float16)v.z; h[3] = (_Float16)v.w;
    *(f16x4*)&lx[nd * XS + i4] = h;
  }
#pragma unroll
  for (int j = 0; j < 16; ++j) {
    int idx = t + 256 * j;
    int o = idx >> 5, i4 = (idx & 31) * 4;
    float4 v = *(const float4*)&w1[(size_t)o * 128 + i4];
    f16x4 h;
    h[0] = (_Float16)v.x; h[1] = (_Float16)v.y;
    h[2] = (_Float16)v.z; h[3] = (_Float16)v.w;
    *(f16x4*)&lw[o * XS + i4] = h;
  }
  __syncthreads();

  int lane = t & 63, wv = t >> 6;
  int m16 = lane & 15, q = lane >> 4;

  f32x4 acc[8];
#pragma unroll
  for (int i = 0; i < 8; ++i) acc[i] = (f32x4){0.f, 0.f, 0.f, 0.f};

#pragma unroll
  for (int c = 0; c < 4; ++c) {
    f16x8 a = *(const f16x8*)&lx[(16 * wv + m16) * XS + c * 32 + q * 8];
#pragma unroll
    for (int tt = 0; tt < 8; ++tt) {
      f16x8 b = *(const f16x8*)&lw[(tt * 16 + m16) * XS + c * 32 + q * 8];
      acc[tt] = __builtin_amdgcn_mfma_f32_16x16x32_f16(a, b, acc[tt], 0, 0, 0);
    }
  }

  // write C to this wave's own lx rows (wave-private; no barrier needed)
#pragma unroll
  for (int tt = 0; tt < 8; ++tt) {
#pragma unroll
    for (int r = 0; r < 4; ++r) {
      lx[(16 * wv + 4 * q + r) * XS + tt * 16 + m16] = (_Float16)acc[tt][r];
    }
  }

  // logits: lane -> node m16, o-part p = q (32 outputs each)
  {
    float ps = 0.f, pd = 0.f;
    int p = q;
#pragma unroll
    for (int k = 0; k < 4; ++k) {
      f16x8 hv = *(const f16x8*)&lx[(16 * wv + m16) * XS + p * 32 + k * 8];
      float4 s0 = *(const float4*)&as1[p * 32 + k * 8];
      float4 s1 = *(const float4*)&as1[p * 32 + k * 8 + 4];
      float4 d0 = *(const float4*)&ad1[p * 32 + k * 8];
      float4 d1 = *(const float4*)&ad1[p * 32 + k * 8 + 4];
      ps += (float)hv[0] * s0.x + (float)hv[1] * s0.y + (float)hv[2] * s0.z +
            (float)hv[3] * s0.w + (float)hv[4] * s1.x + (float)hv[5] * s1.y +
            (float)hv[6] * s1.z + (float)hv[7] * s1.w;
      pd += (float)hv[0] * d0.x + (float)hv[1] * d0.y + (float)hv[2] * d0.z +
            (float)hv[3] * d0.w + (float)hv[4] * d1.x + (float)hv[5] * d1.y +
            (float)hv[6] * d1.z + (float)hv[7] * d1.w;
    }
    ps += __shfl_xor(ps, 16);
    pd += __shfl_xor(pd, 16);
    int n = n0 + 16 * wv + m16;
    if (n < N && (q == 0 || q == 2)) {
      int hh = q >> 1;
      asrc1[2 * n + hh] = ps;
      adst1[2 * n + hh] = pd;
    }
  }

  // coalesced fp16 stores: 16 rows x 16 uint4 per wave -> 4 per lane
#pragma unroll
  for (int i = 0; i < 4; ++i) {
    int m = q + 4 * i;
    int n = n0 + 16 * wv + m;
    if (n < N) {
      uint4 v = *(const uint4*)&lx[(16 * wv + m) * XS + m16 * 8];
      *(uint4*)&xw1h[(size_t)n * 128 + m16 * 8] = v;
    }
  }
}

// ---------------- bucket_build: all-LDS, staged edges, ushort csr ---------

__global__ __launch_bounds__(256) void bucket_build_kernel(const unsigned* __restrict__ binned,
                                                           const int* __restrict__ bincur,
                                                           int2* __restrict__ nodeseg,
                                                           unsigned short* __restrict__ csr,
                                                           unsigned char* __restrict__ dstl,
                                                           int N, int CAP) {
  __shared__ int s_deg[128];
  __shared__ int s_cur[128];
  __shared__ int s_wsum;
  __shared__ unsigned s_edges[CAPMAX];
  int b = blockIdx.x;
  int lo = b * CAP, hi = lo + bincur[b];
  int cnt = hi - lo;
  int t = threadIdx.x;
  if (t < 128) s_deg[t] = 0;
  int stg = min(cnt, CAPMAX);
  for (int i = t; i < stg; i += 256) s_edges[i] = binned[lo + i];
  __syncthreads();
  for (int i = t; i < cnt; i += 256) {
    unsigned e = (i < CAPMAX) ? s_edges[i] : binned[lo + i];
    atomicAdd(&s_deg[e >> 16], 1);
  }
  __syncthreads();
  int lane = t & 63, wv = t >> 6;
  int v = (t < 128) ? s_deg[t] : 0;
  int incl = v;
#pragma unroll
  for (int off = 1; off < 64; off <<= 1) {
    int u = __shfl_up(incl, off);
    if (lane >= off) incl += u;
  }
  if (t == 63) s_wsum = incl;  // wave-0 total
  __syncthreads();
  int excl = incl - v + ((wv == 1) ? s_wsum : 0);
  if (t < 128) {
    int node = (b << BSHIFT) + t;
    if (node < N) nodeseg[node] = make_int2(lo + excl, lo + excl + v);
    s_cur[t] = lo + excl;
  }
  __syncthreads();
  for (int i = t; i < cnt; i += 256) {
    unsigned e = (i < CAPMAX) ? s_edges[i] : binned[lo + i];
    int p = atomicAdd(&s_cur[e >> 16], 1);  // LDS atomic
    csr[p] = (unsigned short)(e & 0xFFFFu);
    dstl[p] = (unsigned char)((e >> 16) & 127u);
  }
}

// ---------------- agg1h: head-split aggregation + partial gemm2 -----------

// wave per (dst node, head). head = blockIdx&1 -> XCD parity via round-robin
// blockIdx->XCD: per-XCD gather working set = one head slice (6.4MB vs 4MB
// L2, was 12.8MB). Head slice = contiguous 128B = one cache line (no
// overfetch). 8 rows x 8 lanes x 16B; 16-edge loop = 2 loads in flight.
// Sits on the ~6.6TB/s request wall — do not restructure (R15 lesson).
__global__ __launch_bounds__(256) void agg1h_kernel(const __half* __restrict__ xw1h,
                                                    const float* __restrict__ asrc1,
                                                    const float* __restrict__ adst1,
                                                    const float* __restrict__ b1,
                                                    const float* __restrict__ w2,
                                                    const unsigned short* __restrict__ csr,
                                                    const int2* __restrict__ nodeseg,
                                                    float* __restrict__ p_out, int N) {
  __shared__ int s_off[4][64];   // row byte offset (s * 256)
  __shared__ float s_w[4][64];   // exp weight for this head
  int lane = threadIdx.x & 63, wv = threadIdx.x >> 6;
  int head = blockIdx.x & 1;
  int d = (blockIdx.x >> 1) * 4 + wv;
  if (d >= N) return;
  int c8 = lane & 7;   // head-local channels 8*c8 .. 8*c8+7
  int row = lane >> 3; // 0..7 edge subgroup
  int2 seg = nodeseg[d];
  int e0 = seg.x, e1 = seg.y;
  float adv = adst1[2 * d + head];
  float wself = __expf(lrelu(asrc1[2 * d + head] + adv));

  const char* xb = (const char*)xw1h + (head << 7) + 16 * c8;

  float a[8];
  float sum = 0.f;
#pragma unroll
  for (int k = 0; k < 8; ++k) a[k] = 0.f;
  if (row == 0) {  // self edge handled once, by row 0
    uint4 r = *(const uint4*)(xb + ((size_t)d << 8));
    const __half2* hp = (const __half2*)&r;
#pragma unroll
    for (int k = 0; k < 4; ++k) {
      float2 v = __half22float2(hp[k]);
      a[2 * k] = wself * v.x;
      a[2 * k + 1] = wself * v.y;
    }
    sum = wself;
  }

  for (int base = e0; base < e1; base += 64) {
    int cnt = min(64, e1 - base);
    if (lane < cnt) {
      int s = (int)csr[base + lane];
      s_off[wv][lane] = s << 8;
      s_w[wv][lane] = __expf(lrelu(asrc1[2 * s + head] + adv));
    }
    // wave-private LDS: same wave wrote it; no barrier needed
    int j = 0;
    for (; j + 15 < cnt; j += 16) {
      int oA = s_off[wv][j + row];
      int oB = s_off[wv][j + 8 + row];
      float wA = s_w[wv][j + row];
      float wB = s_w[wv][j + 8 + row];
      uint4 rA = *(const uint4*)(xb + oA);
      uint4 rB = *(const uint4*)(xb + oB);
      const __half2* hA = (const __half2*)&rA;
      const __half2* hB = (const __half2*)&rB;
#pragma unroll
      for (int k = 0; k < 4; ++k) {
        float2 vA = __half22float2(hA[k]);
        float2 vB = __half22float2(hB[k]);
        a[2 * k] += wA * vA.x + wB * vB.x;
        a[2 * k + 1] += wA * vA.y + wB * vB.y;
      }
      sum += wA + wB;
    }
    for (; j + 7 < cnt; j += 8) {
      int oA = s_off[wv][j + row];
      float wA = s_w[wv][j + row];
      uint4 rA = *(const uint4*)(xb + oA);
      const __half2* hA = (const __half2*)&rA;
#pragma unroll
      for (int k = 0; k < 4; ++k) {
        float2 vA = __half22float2(hA[k]);
        a[2 * k] += wA * vA.x;
        a[2 * k + 1] += wA * vA.y;
      }
      sum += wA;
    }
    if (row < cnt - j) {  // tail: rows 0..cnt-j-1 take one edge each
      int oA = s_off[wv][j + row];
      float wA = s_w[wv][j + row];
      uint4 rA = *(const uint4*)(xb + oA);
      const __half2* hA = (const __half2*)&rA;
#pragma unroll
      for (int k = 0; k < 4; ++k) {
        float2 vA = __half22float2(hA[k]);
        a[2 * k] += wA * vA.x;
        a[2 * k + 1] += wA * vA.y;
      }
      sum += wA;
    }
  }

  // butterfly across the 8 rows -> every lane holds full sums for its c8
#pragma unroll
  for (int k = 0; k < 8; ++k) {
    a[k] += __shfl_xor(a[k], 8);
    a[k] += __shfl_xor(a[k], 16);
    a[k] += __shfl_xor(a[k], 32);
  }
  sum += __shfl_xor(sum, 8);
  sum += __shfl_xor(sum, 16);
  sum += __shfl_xor(sum, 32);

  // h (relu'd, biased) in registers — every lane holds 8 head-local channels
  float inv = 1.f / (sum + 1e-16f);
  int cb = head * 64 + 8 * c8;  // global channel base
  float4 blo = *(const float4*)&b1[cb];
  float4 bhi = *(const float4*)&b1[cb + 4];
  float h[8];
  h[0] = fmaxf(a[0] * inv + blo.x, 0.f);
  h[1] = fmaxf(a[1] * inv + blo.y, 0.f);
  h[2] = fmaxf(a[2] * inv + blo.z, 0.f);
  h[3] = fmaxf(a[3] * inv + blo.w, 0.f);
  h[4] = fmaxf(a[4] * inv + bhi.x, 0.f);
  h[5] = fmaxf(a[5] * inv + bhi.y, 0.f);
  h[6] = fmaxf(a[6] * inv + bhi.z, 0.f);
  h[7] = fmaxf(a[7] * inv + bhi.w, 0.f);

  // partial gemm2 over this head's 64 channels: row r computes channels
  // 2r, 2r+1 (butterfly over the 8 octets within the row)
  float p0, p1;
  {
    const float* wr0 = &w2[(size_t)(2 * row) * 128 + cb];
    const float* wr1 = &w2[(size_t)(2 * row + 1) * 128 + cb];
    float4 w0lo = *(const float4*)wr0;
    float4 w0hi = *(const float4*)(wr0 + 4);
    float4 w1lo = *(const float4*)wr1;
    float4 w1hi = *(const float4*)(wr1 + 4);
    p0 = h[0] * w0lo.x + h[1] * w0lo.y + h[2] * w0lo.z + h[3] * w0lo.w +
         h[4] * w0hi.x + h[5] * w0hi.y + h[6] * w0hi.z + h[7] * w0hi.w;
    p1 = h[0] * w1lo.x + h[1] * w1lo.y + h[2] * w1lo.z + h[3] * w1lo.w +
         h[4] * w1hi.x + h[5] * w1hi.y + h[6] * w1hi.z + h[7] * w1hi.w;
  }
#pragma unroll
  for (int k = 1; k < 8; k <<= 1) {
    p0 += __shfl_xor(p0, k);
    p1 += __shfl_xor(p1, k);
  }
  if (c8 == 0) {  // one lane per row stores its 2 partial channels (8B)
    *(float2*)&p_out[(size_t)d * 32 + head * 16 + 2 * row] =
        make_float2(p0, p1);
  }
}

// ---------------- combine: xw2 = p0 + p1, fp16 store + layer-2 logits -----

__global__ __launch_bounds__(256) void combine_kernel(const float* __restrict__ p,
                                                      const float* __restrict__ as2,
                                                      const float* __restrict__ ad2,
                                                      __half* __restrict__ xw2h,
                                                      float* __restrict__ asrc2,
                                                      float* __restrict__ adst2, int N) {
  int idx = blockIdx.x * 256 + threadIdx.x;
  int node = idx >> 4, c = idx & 15;
  if (node >= N) return;
  float v = p[(size_t)node * 32 + c] + p[(size_t)node * 32 + 16 + c];
  xw2h[(size_t)node * 16 + c] = __float2half(v);
  float qs = v * as2[c], qd = v * ad2[c];
#pragma unroll
  for (int k = 1; k < 16; k <<= 1) {
    qs += __shfl_xor(qs, k);
    qd += __shfl_xor(qd, k);
  }
  if (c == 0) {
    asrc2[node] = qs;
    adst2[node] = qd;
  }
}

// ---------------- wprep2: per-edge layer-2 exp weights (CSR-aligned) ------

// Streaming, massively parallel: moves the random asrc2 gather + exp out of
// agg2's per-wave serial chain. grid = (ceil(CAP/256), B).
__global__ __launch_bounds__(256) void wprep2_kernel(const unsigned short* __restrict__ csr,
                                                     const unsigned char* __restrict__ dstl,
                                                     const int* __restrict__ bincur,
                                                     const float* __restrict__ asrc2,
                                                     const float* __restrict__ adst2,
                                                     float* __restrict__ wexp2, int CAP) {
  int b = blockIdx.y;
  int slot = blockIdx.x * 256 + threadIdx.x;
  if (slot >= bincur[b]) return;
  int i = b * CAP + slot;
  int s = (int)csr[i];
  int d = (b << BSHIFT) + (int)dstl[i];
  wexp2[i] = __expf(lrelu(asrc2[s] + adst2[d]));
}

// ---------------- agg2: chain-shortened, 8-deep one-shot gathers ----------

// wave per dst node. 8 rows x 8 lanes x 4B. Staging = two coalesced reads
// (csr + wexp2); all <=8 row gathers of the chunk issued before consumption
// (deg~33 => one fully pipelined burst per node). Table is L2-resident
// (1.6MB) => latency was the binder, not bandwidth.
__global__ __launch_bounds__(256) void agg2_kernel(const __half* __restrict__ xw2h,
                                                   const float* __restrict__ asrc2,
                                                   const float* __restrict__ adst2,
                                                   const float* __restrict__ b2,
                                                   const unsigned short* __restrict__ csr,
                                                   const float* __restrict__ wexp2,
                                                   const int2* __restrict__ nodeseg,
                                                   float* __restrict__ out, int N) {
  __shared__ int s_off[4][64];   // row byte offset (s * 32)
  __shared__ float s_w[4][64];
  int lane = threadIdx.x & 63, wv = threadIdx.x >> 6;
  int d = blockIdx.x * 4 + wv;
  if (d >= N) return;
  int c2 = lane & 7;   // channels 2*c2, 2*c2+1
  int row = lane >> 3; // 0..7
  int2 seg = nodeseg[d];
  int e0 = seg.x, e1 = seg.y;
  float wself = __expf(lrelu(asrc2[d] + adst2[d]));
  const char* xb = (const char*)xw2h + 4 * c2;

  float a0 = 0.f, a1 = 0.f, sum = 0.f;
  if (row == 0) {
    float2 v = __half22float2(*(const __half2*)(xb + (size_t)d * 32));
    a0 = wself * v.x;
    a1 = wself * v.y;
    sum = wself;
  }
  for (int base = e0; base < e1; base += 64) {
    int cnt = min(64, e1 - base);
    if (lane < cnt) {
      s_off[wv][lane] = ((int)csr[base + lane]) << 5;
      s_w[wv][lane] = wexp2[base + lane];
    }
    // wave-private LDS: same wave wrote it; no barrier needed.
    // one-shot: issue every gather of this chunk, then consume.
    float2 vv[8];
    float ww[8];
#pragma unroll
    for (int k = 0; k < 8; ++k) {
      int e = row + 8 * k;
      if (e < cnt) {
        vv[k] = __half22float2(*(const __half2*)(xb + s_off[wv][e]));
        ww[k] = s_w[wv][e];
      }
    }
#pragma unroll
    for (int k = 0; k < 8; ++k) {
      int e = row + 8 * k;
      if (e < cnt) {
        a0 += ww[k] * vv[k].x;
        a1 += ww[k] * vv[k].y;
        sum += ww[k];
      }
    }
  }
#pragma unroll
  for (int k = 8; k < 64; k <<= 1) {
    a0 += __shfl_xor(a0, k);
    a1 += __shfl_xor(a1, k);
    sum += __shfl_xor(sum, k);
  }
  if (lane < 8) {
    float inv = 1.f / (sum + 1e-16f);
    float2 r;
    r.x = a0 * inv + b2[2 * c2];
    r.y = a1 * inv + b2[2 * c2 + 1];
    *(float2*)&out[(size_t)d * 16 + 2 * c2] = r;
  }
}

// ---------------------------------------------------------------------------

extern "C" void kernel_launch(void* const* d_in, const int* in_sizes, int n_in,
                              void* d_out, int out_size, void* d_ws, size_t ws_size,
                              hipStream_t stream) {
  const float* x = (const float*)d_in[0];
  const int* ei = (const int*)d_in[1];
  const float* w1 = (const float*)d_in[2];
  const float* as1 = (const float*)d_in[3];
  const float* ad1 = (const float*)d_in[4];
  const float* b1 = (const float*)d_in[5];
  const float* w2 = (const float*)d_in[6];
  const float* as2 = (const float*)d_in[7];
  const float* ad2 = (const float*)d_in[8];
  const float* b2 = (const float*)d_in[9];
  float* out = (float*)d_out;

  int N = in_sizes[0] / 128;
  int E = in_sizes[1] / 2;
  const int* srcp = ei;
  const int* dstp = ei + E;

  int B = (N + (1 << BSHIFT) - 1) >> BSHIFT;  // 391 buckets (N<=65536 req'd)
  // bucket capacity: mean + 25% slack (+512), rounded to 256 (Poisson ~16sig)
  int mean = (E + B - 1) / B;
  int CAP = (mean + mean / 4 + 512 + 255) & ~255;
  const int NB = 256;  // partition blocks
  int CH = (E + NB - 1) / NB;  // 6250 -> 25 KB LDS packing buffer
  int GB = (N + 63) / 64;  // gemm1 tiles

  char* p = (char*)d_ws;
  auto alloc = [&](size_t bytes) -> void* {
    void* r = (void*)p;
    p += (bytes + 255) & ~(size_t)255;
    return r;
  };
  __half* xw1h = (__half*)alloc((size_t)N * 128 * 2);
  float* asrc1 = (float*)alloc((size_t)N * 2 * 4);
  float* adst1 = (float*)alloc((size_t)N * 2 * 4);
  __half* xw2h = (__half*)alloc((size_t)N * 16 * 2);
  float* asrc2 = (float*)alloc((size_t)N * 4);
  float* adst2 = (float*)alloc((size_t)N * 4);
  float* p_out = (float*)alloc((size_t)N * 32 * 4);  // [N][head][16] fp32
  int2* nodeseg = (int2*)alloc((size_t)N * 8);
  unsigned short* csr = (unsigned short*)alloc((size_t)B * CAP * 2);
  unsigned char* dstl = (unsigned char*)alloc((size_t)B * CAP);
  float* wexp2 = (float*)alloc((size_t)B * CAP * 4);
  unsigned* binned = (unsigned*)alloc((size_t)B * CAP * 4);
  int* bincur = (int*)alloc((size_t)B * 4);

  hipMemsetAsync(bincur, 0, (size_t)B * 4, stream);
  part_gemm1_kernel<<<NB + GB, 256, 0, stream>>>(srcp, dstp, bincur, binned,
                                                 E, B, CH, CAP, NB,
                                                 x, w1, as1, ad1, xw1h, asrc1, adst1, N);
  bucket_build_kernel<<<B, 256, 0, stream>>>(binned, bincur, nodeseg, csr, dstl, N, CAP);
  agg1h_kernel<<<2 * ((N + 3) / 4), 256, 0, stream>>>(xw1h, asrc1, adst1, b1, w2,
                                                      csr, nodeseg, p_out, N);
  combine_kernel<<<(N * 16 + 255) / 256, 256, 0, stream>>>(p_out, as2, ad2,
                                                           xw2h, asrc2, adst2, N);
  dim3 wg((CAP + 255) / 256, B);
  wprep2_kernel<<<wg, 256, 0, stream>>>(csr, dstl, bincur, asrc2, adst2, wexp2, CAP);
  agg2_kernel<<<(N + 3) / 4, 256, 0, stream>>>(xw2h, asrc2, adst2, b2, csr, wexp2,
                                               nodeseg, out, N);
}

// Round 4
// 218.724 us; speedup vs baseline: 1.3185x; 1.0331x over previous
//
#include <hip/hip_runtime.h>
#include <hip/hip_fp16.h>

// ---------------------------------------------------------------------------
// GAT 2-layer forward. N=50000 nodes, F=128, E=1.6M random edges (+N implicit
// self loops). L1: H=2,C=64 concat -> relu. L2: H=1,C=16.
//
// Dispatches: memset -> {partition || gemm1} -> bucket_build -> agg1h
// (head-split) -> combine -> agg2.
//
// Model (R14-R16 measured): both aggregations sit on a random-TRANSACTION
// wall (a 4B random read moves a 64B line; agg1h: 3.2M row txns + 3.2M
// alpha txns = 68us; R1 agg2: 1.6M row + 1.6M alpha txns ~= 55us). R16's
// wprep2 merely relocated alpha txns -> +10us. Levers that work = fewer
// txns per edge:
//   * agg2 packed record (this): rec2[s] = [alpha f32 | 16 fp16 | pad] at
//     64B stride -> ONE txn per edge (16 sublanes x 4B; alpha broadcast by
//     intra-group shfl). 3.2M -> 1.6M txns.
//   * agg1h alpha plane split (this): asrc1 stored [head][N] so head-pinned
//     blocks see full 64B alpha lines (was interleaved [n][head], 50%
//     density). Row gathers (128B/edge/head) are irreducible payload.
//   * head-split agg1 (R14): head=blockIdx&1 -> XCD parity, per-XCD working
//     set 12.8->6.4MB (FETCH 157->109MB).
// R15 lesson: do NOT trade TLP for chain amortization (2.1x regression).
//
// gemm1: fp16 MFMA (mfma_f32_16x16x32_f16), LDS stride-136 fp16, fp32
// accumulate, epilogue stages C through LDS for coalesced fp16 stores +
// fused layer-1 logits. Softmax without max-shift (logits bounded, fp32 exp
// safe; ratio identical to reference in exact math). xw stored fp16.
// ---------------------------------------------------------------------------

#define BSHIFT 7                 // 128 dst nodes per bucket
#define MAXB 512                 // supports N <= 65536
#define CAPMAX 6144              // LDS edge-staging bound (entries)
#define XS 136

using f16x8 = __attribute__((ext_vector_type(8))) _Float16;
using f16x4 = __attribute__((ext_vector_type(4))) _Float16;
using f32x4 = __attribute__((ext_vector_type(4))) float;

__device__ __forceinline__ float lrelu(float a) { return fmaxf(a, 0.2f * a); }

// ---------------- fused: partition (blocks 0..NB-1) + gemm1 (rest) --------

__global__ __launch_bounds__(256) void part_gemm1_kernel(
    const int* __restrict__ src, const int* __restrict__ dst,
    int* __restrict__ bincur, unsigned* __restrict__ binned,
    int E, int B, int CH, int CAP, int NB,
    const float* __restrict__ x, const float* __restrict__ w1,
    const float* __restrict__ as1, const float* __restrict__ ad1,
    __half* __restrict__ xw1h, float* __restrict__ asrc1h,
    float* __restrict__ adst1, int N) {
  __shared__ __align__(16) char smem[(64 + 128) * XS * 2];  // 52224 B
  int t = threadIdx.x;

  if (blockIdx.x < (unsigned)NB) {
    // ---- partition: single global pass; pack edges into LDS ----
    int* s_h = (int*)smem;
    int* s_base = s_h + MAXB;
    int* s_cur = s_base + MAXB;
    unsigned* s_pack = (unsigned*)(s_cur + MAXB);  // CH <= 6250 -> 25 KB
    for (int i = t; i < B; i += 256) s_h[i] = 0;
    __syncthreads();
    int lo = blockIdx.x * CH;
    int cnt = min(CH, E - lo);
    for (int i = t; i < cnt; i += 256) {
      int d = dst[lo + i];
      int s = src[lo + i];
      atomicAdd(&s_h[d >> BSHIFT], 1);
      s_pack[i] = (unsigned)s | ((unsigned)(d & 127) << 16) |
                  ((unsigned)(d >> BSHIFT) << 23);
    }
    __syncthreads();
    for (int i = t; i < B; i += 256) {
      int c = s_h[i];
      s_base[i] = c ? (i * CAP + atomicAdd(&bincur[i], c)) : 0;
      s_cur[i] = 0;
    }
    __syncthreads();
    for (int i = t; i < cnt; i += 256) {
      unsigned e = s_pack[i];
      int b = e >> 23;
      int r = atomicAdd(&s_cur[b], 1);
      binned[s_base[b] + r] = e & 0x7FFFFFu;
    }
    return;
  }

  // ---- gemm1: 64-node tile, fp16 MFMA, fused logits ----
  _Float16* lx = (_Float16*)smem;
  _Float16* lw = lx + 64 * XS;
  int n0 = (blockIdx.x - NB) * 64;

#pragma unroll
  for (int j = 0; j < 8; ++j) {
    int idx = t + 256 * j;
    int nd = idx >> 5, i4 = (idx & 31) * 4;
    int gn = n0 + nd;
    float4 v = (gn < N) ? *(const float4*)&x[(size_t)gn * 128 + i4]
                        : make_float4(0.f, 0.f, 0.f, 0.f);
    f16x4 h;
    h[0] = (_Float16)v.x; h[1] = (_Float16)v.y;
    h[2] = (_Float16)v.z; h[3] = (_Float16)v.w;
    *(f16x4*)&lx[nd * XS + i4] = h;
  }
#pragma unroll
  for (int j = 0; j < 16; ++j) {
    int idx = t + 256 * j;
    int o = idx >> 5, i4 = (idx & 31) * 4;
    float4 v = *(const float4*)&w1[(size_t)o * 128 + i4];
    f16x4 h;
    h[0] = (_Float16)v.x; h[1] = (_Float16)v.y;
    h[2] = (_Float16)v.z; h[3] = (_Float16)v.w;
    *(f16x4*)&lw[o * XS + i4] = h;
  }
  __syncthreads();

  int lane = t & 63, wv = t >> 6;
  int m16 = lane & 15, q = lane >> 4;

  f32x4 acc[8];
#pragma unroll
  for (int i = 0; i < 8; ++i) acc[i] = (f32x4){0.f, 0.f, 0.f, 0.f};

#pragma unroll
  for (int c = 0; c < 4; ++c) {
    f16x8 a = *(const f16x8*)&lx[(16 * wv + m16) * XS + c * 32 + q * 8];
#pragma unroll
    for (int tt = 0; tt < 8; ++tt) {
      f16x8 b = *(const f16x8*)&lw[(tt * 16 + m16) * XS + c * 32 + q * 8];
      acc[tt] = __builtin_amdgcn_mfma_f32_16x16x32_f16(a, b, acc[tt], 0, 0, 0);
    }
  }

  // write C to this wave's own lx rows (wave-private; no barrier needed)
#pragma unroll
  for (int tt = 0; tt < 8; ++tt) {
#pragma unroll
    for (int r = 0; r < 4; ++r) {
      lx[(16 * wv + 4 * q + r) * XS + tt * 16 + m16] = (_Float16)acc[tt][r];
    }
  }

  // logits: lane -> node m16, o-part p = q (32 outputs each)
  {
    float ps = 0.f, pd = 0.f;
    int p = q;
#pragma unroll
    for (int k = 0; k < 4; ++k) {
      f16x8 hv = *(const f16x8*)&lx[(16 * wv + m16) * XS + p * 32 + k * 8];
      float4 s0 = *(const float4*)&as1[p * 32 + k * 8];
      float4 s1 = *(const float4*)&as1[p * 32 + k * 8 + 4];
      float4 d0 = *(const float4*)&ad1[p * 32 + k * 8];
      float4 d1 = *(const float4*)&ad1[p * 32 + k * 8 + 4];
      ps += (float)hv[0] * s0.x + (float)hv[1] * s0.y + (float)hv[2] * s0.z +
            (float)hv[3] * s0.w + (float)hv[4] * s1.x + (float)hv[5] * s1.y +
            (float)hv[6] * s1.z + (float)hv[7] * s1.w;
      pd += (float)hv[0] * d0.x + (float)hv[1] * d0.y + (float)hv[2] * d0.z +
            (float)hv[3] * d0.w + (float)hv[4] * d1.x + (float)hv[5] * d1.y +
            (float)hv[6] * d1.z + (float)hv[7] * d1.w;
    }
    ps += __shfl_xor(ps, 16);
    pd += __shfl_xor(pd, 16);
    int n = n0 + 16 * wv + m16;
    if (n < N && (q == 0 || q == 2)) {
      int hh = q >> 1;
      asrc1h[hh * N + n] = ps;   // [head][N] plane (R17: alpha line density 2x)
      adst1[2 * n + hh] = pd;
    }
  }

  // coalesced fp16 stores: 16 rows x 16 uint4 per wave -> 4 per lane
#pragma unroll
  for (int i = 0; i < 4; ++i) {
    int m = q + 4 * i;
    int n = n0 + 16 * wv + m;
    if (n < N) {
      uint4 v = *(const uint4*)&lx[(16 * wv + m) * XS + m16 * 8];
      *(uint4*)&xw1h[(size_t)n * 128 + m16 * 8] = v;
    }
  }
}

// ---------------- bucket_build: all-LDS, staged edges, ushort csr ---------

__global__ __launch_bounds__(256) void bucket_build_kernel(const unsigned* __restrict__ binned,
                                                           const int* __restrict__ bincur,
                                                           int2* __restrict__ nodeseg,
                                                           unsigned short* __restrict__ csr,
                                                           int N, int CAP) {
  __shared__ int s_deg[128];
  __shared__ int s_cur[128];
  __shared__ int s_wsum;
  __shared__ unsigned s_edges[CAPMAX];
  int b = blockIdx.x;
  int lo = b * CAP, hi = lo + bincur[b];
  int cnt = hi - lo;
  int t = threadIdx.x;
  if (t < 128) s_deg[t] = 0;
  int stg = min(cnt, CAPMAX);
  for (int i = t; i < stg; i += 256) s_edges[i] = binned[lo + i];
  __syncthreads();
  for (int i = t; i < cnt; i += 256) {
    unsigned e = (i < CAPMAX) ? s_edges[i] : binned[lo + i];
    atomicAdd(&s_deg[e >> 16], 1);
  }
  __syncthreads();
  int lane = t & 63, wv = t >> 6;
  int v = (t < 128) ? s_deg[t] : 0;
  int incl = v;
#pragma unroll
  for (int off = 1; off < 64; off <<= 1) {
    int u = __shfl_up(incl, off);
    if (lane >= off) incl += u;
  }
  if (t == 63) s_wsum = incl;  // wave-0 total
  __syncthreads();
  int excl = incl - v + ((wv == 1) ? s_wsum : 0);
  if (t < 128) {
    int node = (b << BSHIFT) + t;
    if (node < N) nodeseg[node] = make_int2(lo + excl, lo + excl + v);
    s_cur[t] = lo + excl;
  }
  __syncthreads();
  for (int i = t; i < cnt; i += 256) {
    unsigned e = (i < CAPMAX) ? s_edges[i] : binned[lo + i];
    int p = atomicAdd(&s_cur[e >> 16], 1);  // LDS atomic
    csr[p] = (unsigned short)(e & 0xFFFFu);
  }
}

// ---------------- agg1h: head-split aggregation + partial gemm2 -----------

// wave per (dst node, head). head = blockIdx&1 -> XCD parity via round-robin
// blockIdx->XCD: per-XCD gather working set = one head slice (6.4MB vs 4MB
// L2, was 12.8MB). Head slice = contiguous 128B = one cache line (no
// overfetch). 8 rows x 8 lanes x 16B; 16-edge loop = 2 loads in flight.
// Sits on the txn wall — do not trade TLP for chain depth (R15 lesson).
__global__ __launch_bounds__(256) void agg1h_kernel(const __half* __restrict__ xw1h,
                                                    const float* __restrict__ asrc1h,
                                                    const float* __restrict__ adst1,
                                                    const float* __restrict__ b1,
                                                    const float* __restrict__ w2,
                                                    const unsigned short* __restrict__ csr,
                                                    const int2* __restrict__ nodeseg,
                                                    float* __restrict__ p_out, int N) {
  __shared__ int s_off[4][64];   // row byte offset (s * 256)
  __shared__ float s_w[4][64];   // exp weight for this head
  int lane = threadIdx.x & 63, wv = threadIdx.x >> 6;
  int head = blockIdx.x & 1;
  int d = (blockIdx.x >> 1) * 4 + wv;
  if (d >= N) return;
  int c8 = lane & 7;   // head-local channels 8*c8 .. 8*c8+7
  int row = lane >> 3; // 0..7 edge subgroup
  int2 seg = nodeseg[d];
  int e0 = seg.x, e1 = seg.y;
  const float* asp = asrc1h + (size_t)head * N;  // this head's alpha plane
  float adv = adst1[2 * d + head];
  float wself = __expf(lrelu(asp[d] + adv));

  const char* xb = (const char*)xw1h + (head << 7) + 16 * c8;

  float a[8];
  float sum = 0.f;
#pragma unroll
  for (int k = 0; k < 8; ++k) a[k] = 0.f;
  if (row == 0) {  // self edge handled once, by row 0
    uint4 r = *(const uint4*)(xb + ((size_t)d << 8));
    const __half2* hp = (const __half2*)&r;
#pragma unroll
    for (int k = 0; k < 4; ++k) {
      float2 v = __half22float2(hp[k]);
      a[2 * k] = wself * v.x;
      a[2 * k + 1] = wself * v.y;
    }
    sum = wself;
  }

  for (int base = e0; base < e1; base += 64) {
    int cnt = min(64, e1 - base);
    if (lane < cnt) {
      int s = (int)csr[base + lane];
      s_off[wv][lane] = s << 8;
      s_w[wv][lane] = __expf(lrelu(asp[s] + adv));
    }
    // wave-private LDS: same wave wrote it; no barrier needed
    int j = 0;
    for (; j + 15 < cnt; j += 16) {
      int oA = s_off[wv][j + row];
      int oB = s_off[wv][j + 8 + row];
      float wA = s_w[wv][j + row];
      float wB = s_w[wv][j + 8 + row];
      uint4 rA = *(const uint4*)(xb + oA);
      uint4 rB = *(const uint4*)(xb + oB);
      const __half2* hA = (const __half2*)&rA;
      const __half2* hB = (const __half2*)&rB;
#pragma unroll
      for (int k = 0; k < 4; ++k) {
        float2 vA = __half22float2(hA[k]);
        float2 vB = __half22float2(hB[k]);
        a[2 * k] += wA * vA.x + wB * vB.x;
        a[2 * k + 1] += wA * vA.y + wB * vB.y;
      }
      sum += wA + wB;
    }
    for (; j + 7 < cnt; j += 8) {
      int oA = s_off[wv][j + row];
      float wA = s_w[wv][j + row];
      uint4 rA = *(const uint4*)(xb + oA);
      const __half2* hA = (const __half2*)&rA;
#pragma unroll
      for (int k = 0; k < 4; ++k) {
        float2 vA = __half22float2(hA[k]);
        a[2 * k] += wA * vA.x;
        a[2 * k + 1] += wA * vA.y;
      }
      sum += wA;
    }
    if (row < cnt - j) {  // tail: rows 0..cnt-j-1 take one edge each
      int oA = s_off[wv][j + row];
      float wA = s_w[wv][j + row];
      uint4 rA = *(const uint4*)(xb + oA);
      const __half2* hA = (const __half2*)&rA;
#pragma unroll
      for (int k = 0; k < 4; ++k) {
        float2 vA = __half22float2(hA[k]);
        a[2 * k] += wA * vA.x;
        a[2 * k + 1] += wA * vA.y;
      }
      sum += wA;
    }
  }

  // butterfly across the 8 rows -> every lane holds full sums for its c8
#pragma unroll
  for (int k = 0; k < 8; ++k) {
    a[k] += __shfl_xor(a[k], 8);
    a[k] += __shfl_xor(a[k], 16);
    a[k] += __shfl_xor(a[k], 32);
  }
  sum += __shfl_xor(sum, 8);
  sum += __shfl_xor(sum, 16);
  sum += __shfl_xor(sum, 32);

  // h (relu'd, biased) in registers — every lane holds 8 head-local channels
  float inv = 1.f / (sum + 1e-16f);
  int cb = head * 64 + 8 * c8;  // global channel base
  float4 blo = *(const float4*)&b1[cb];
  float4 bhi = *(const float4*)&b1[cb + 4];
  float h[8];
  h[0] = fmaxf(a[0] * inv + blo.x, 0.f);
  h[1] = fmaxf(a[1] * inv + blo.y, 0.f);
  h[2] = fmaxf(a[2] * inv + blo.z, 0.f);
  h[3] = fmaxf(a[3] * inv + blo.w, 0.f);
  h[4] = fmaxf(a[4] * inv + bhi.x, 0.f);
  h[5] = fmaxf(a[5] * inv + bhi.y, 0.f);
  h[6] = fmaxf(a[6] * inv + bhi.z, 0.f);
  h[7] = fmaxf(a[7] * inv + bhi.w, 0.f);

  // partial gemm2 over this head's 64 channels: row r computes channels
  // 2r, 2r+1 (butterfly over the 8 octets within the row)
  float p0, p1;
  {
    const float* wr0 = &w2[(size_t)(2 * row) * 128 + cb];
    const float* wr1 = &w2[(size_t)(2 * row + 1) * 128 + cb];
    float4 w0lo = *(const float4*)wr0;
    float4 w0hi = *(const float4*)(wr0 + 4);
    float4 w1lo = *(const float4*)wr1;
    float4 w1hi = *(const float4*)(wr1 + 4);
    p0 = h[0] * w0lo.x + h[1] * w0lo.y + h[2] * w0lo.z + h[3] * w0lo.w +
         h[4] * w0hi.x + h[5] * w0hi.y + h[6] * w0hi.z + h[7] * w0hi.w;
    p1 = h[0] * w1lo.x + h[1] * w1lo.y + h[2] * w1lo.z + h[3] * w1lo.w +
         h[4] * w1hi.x + h[5] * w1hi.y + h[6] * w1hi.z + h[7] * w1hi.w;
  }
#pragma unroll
  for (int k = 1; k < 8; k <<= 1) {
    p0 += __shfl_xor(p0, k);
    p1 += __shfl_xor(p1, k);
  }
  if (c8 == 0) {  // one lane per row stores its 2 partial channels (8B)
    *(float2*)&p_out[(size_t)d * 32 + head * 16 + 2 * row] =
        make_float2(p0, p1);
  }
}

// ---------------- combine: rec2[s] = [alpha | 16 fp16 row], adst2 ---------

// rec2 record (64B stride, 64B-aligned): byte 0..3 = asrc2 (f32);
// bytes 4..35 = xw2 row as 16 fp16; rest pad. One L2 line per src node ->
// agg2 fetches everything for an edge in a single transaction.
__global__ __launch_bounds__(256) void combine_kernel(const float* __restrict__ p,
                                                      const float* __restrict__ as2,
                                                      const float* __restrict__ ad2,
                                                      char* __restrict__ rec2,
                                                      float* __restrict__ adst2, int N) {
  int idx = blockIdx.x * 256 + threadIdx.x;
  int node = idx >> 4, c = idx & 15;
  if (node >= N) return;
  float v = p[(size_t)node * 32 + c] + p[(size_t)node * 32 + 16 + c];
  float qs = v * as2[c], qd = v * ad2[c];
#pragma unroll
  for (int k = 1; k < 16; k <<= 1) {
    qs += __shfl_xor(qs, k);
    qd += __shfl_xor(qd, k);
  }
  char* rb = rec2 + (size_t)node * 64;
  ((__half*)(rb + 4))[c] = __float2half(v);
  if (c == 0) {
    *(float*)rb = qs;
    adst2[node] = qd;
  }
}

// ---------------- agg2: packed-record, ONE txn per edge -------------------

// wave per dst node. 16 sublanes per edge x 4 edge-groups: each lane loads
// one dword of the 64B record; sublane 0 = alpha (broadcast via shfl to its
// group), sublanes 1..8 = the 8 half2 channel dwords. Per edge exactly one
// 64B L2 transaction (was 2: row + alpha gather). 4 loads in flight/lane.
__global__ __launch_bounds__(256) void agg2_kernel(const char* __restrict__ rec2,
                                                   const float* __restrict__ adst2,
                                                   const float* __restrict__ b2,
                                                   const unsigned short* __restrict__ csr,
                                                   const int2* __restrict__ nodeseg,
                                                   float* __restrict__ out, int N) {
  __shared__ int s_off[4][64];   // record byte offset (s * 64)
  int lane = threadIdx.x & 63, wv = threadIdx.x >> 6;
  int d = blockIdx.x * 4 + wv;
  if (d >= N) return;
  int sub = lane & 15;  // record dword index
  int g = lane >> 4;    // edge group 0..3
  int2 seg = nodeseg[d];
  int e0 = seg.x, e1 = seg.y;
  float advd = adst2[d];

  float a0 = 0.f, a1 = 0.f, sum = 0.f;

  // self edge: group 0 only
  if (g == 0) {
    unsigned rv = *(const unsigned*)(rec2 + (size_t)d * 64 + 4 * sub);
    float al = __uint_as_float(__shfl(rv, 0));
    float w = __expf(lrelu(al + advd));
    float2 v = __half22float2(*(const __half2*)&rv);
    if (sub >= 1 && sub <= 8) {
      a0 = w * v.x;
      a1 = w * v.y;
    } else if (sub == 0) {
      sum = w;
    }
  }

  for (int base = e0; base < e1; base += 64) {
    int cnt = min(64, e1 - base);
    if (lane < cnt) s_off[wv][lane] = ((int)csr[base + lane]) << 6;
    // wave-private LDS: same wave wrote it; no barrier needed.
    for (int j = 0; j < cnt; j += 16) {
      unsigned rv[4];
#pragma unroll
      for (int k = 0; k < 4; ++k) {
        int e = j + 4 * k + g;
        if (e < cnt) rv[k] = *(const unsigned*)(rec2 + s_off[wv][e] + 4 * sub);
      }
#pragma unroll
      for (int k = 0; k < 4; ++k) {
        int e = j + 4 * k + g;
        if (e < cnt) {
          float al = __uint_as_float(__shfl(rv[k], lane & 48));  // group's sub0
          float w = __expf(lrelu(al + advd));
          float2 v = __half22float2(*(const __half2*)&rv[k]);
          if (sub >= 1 && sub <= 8) {
            a0 += w * v.x;
            a1 += w * v.y;
          } else if (sub == 0) {
            sum += w;
          }
        }
      }
    }
  }

  // reduce across the 4 edge groups (same sub, lanes differ in bits 4,5)
  a0 += __shfl_xor(a0, 16);
  a0 += __shfl_xor(a0, 32);
  a1 += __shfl_xor(a1, 16);
  a1 += __shfl_xor(a1, 32);
  sum += __shfl_xor(sum, 16);
  sum += __shfl_xor(sum, 32);
  float st = __shfl(sum, 0);  // total weight (held by sub==0 lanes)

  if (g == 0 && sub >= 1 && sub <= 8) {
    int c0 = 2 * (sub - 1);
    float inv = 1.f / (st + 1e-16f);
    float2 bb = *(const float2*)&b2[c0];
    float2 r;
    r.x = a0 * inv + bb.x;
    r.y = a1 * inv + bb.y;
    *(float2*)&out[(size_t)d * 16 + c0] = r;
  }
}

// ---------------------------------------------------------------------------

extern "C" void kernel_launch(void* const* d_in, const int* in_sizes, int n_in,
                              void* d_out, int out_size, void* d_ws, size_t ws_size,
                              hipStream_t stream) {
  const float* x = (const float*)d_in[0];
  const int* ei = (const int*)d_in[1];
  const float* w1 = (const float*)d_in[2];
  const float* as1 = (const float*)d_in[3];
  const float* ad1 = (const float*)d_in[4];
  const float* b1 = (const float*)d_in[5];
  const float* w2 = (const float*)d_in[6];
  const float* as2 = (const float*)d_in[7];
  const float* ad2 = (const float*)d_in[8];
  const float* b2 = (const float*)d_in[9];
  float* out = (float*)d_out;

  int N = in_sizes[0] / 128;
  int E = in_sizes[1] / 2;
  const int* srcp = ei;
  const int* dstp = ei + E;

  int B = (N + (1 << BSHIFT) - 1) >> BSHIFT;  // 391 buckets (N<=65536 req'd)
  // bucket capacity: mean + 25% slack (+512), rounded to 256 (Poisson ~16sig)
  int mean = (E + B - 1) / B;
  int CAP = (mean + mean / 4 + 512 + 255) & ~255;
  const int NB = 256;  // partition blocks
  int CH = (E + NB - 1) / NB;  // 6250 -> 25 KB LDS packing buffer
  int GB = (N + 63) / 64;  // gemm1 tiles

  char* p = (char*)d_ws;
  auto alloc = [&](size_t bytes) -> void* {
    void* r = (void*)p;
    p += (bytes + 255) & ~(size_t)255;
    return r;
  };
  __half* xw1h = (__half*)alloc((size_t)N * 128 * 2);
  float* asrc1h = (float*)alloc((size_t)N * 2 * 4);  // [head][N] planes
  float* adst1 = (float*)alloc((size_t)N * 2 * 4);
  char* rec2 = (char*)alloc((size_t)N * 64);         // [alpha|16 fp16|pad]
  float* adst2 = (float*)alloc((size_t)N * 4);
  float* p_out = (float*)alloc((size_t)N * 32 * 4);  // [N][head][16] fp32
  int2* nodeseg = (int2*)alloc((size_t)N * 8);
  unsigned short* csr = (unsigned short*)alloc((size_t)B * CAP * 2);
  unsigned* binned = (unsigned*)alloc((size_t)B * CAP * 4);
  int* bincur = (int*)alloc((size_t)B * 4);

  hipMemsetAsync(bincur, 0, (size_t)B * 4, stream);
  part_gemm1_kernel<<<NB + GB, 256, 0, stream>>>(srcp, dstp, bincur, binned,
                                                 E, B, CH, CAP, NB,
                                                 x, w1, as1, ad1, xw1h, asrc1h, adst1, N);
  bucket_build_kernel<<<B, 256, 0, stream>>>(binned, bincur, nodeseg, csr, N, CAP);
  agg1h_kernel<<<2 * ((N + 3) / 4), 256, 0, stream>>>(xw1h, asrc1h, adst1, b1, w2,
                                                      csr, nodeseg, p_out, N);
  combine_kernel<<<(N * 16 + 255) / 256, 256, 0, stream>>>(p_out, as2, ad2,
                                                           rec2, adst2, N);
  agg2_kernel<<<(N + 3) / 4, 256, 0, stream>>>(rec2, adst2, b2, csr, nodeseg, out, N);
}

// Round 5
// 206.251 us; speedup vs baseline: 1.3983x; 1.0605x over previous
//
#include <hip/hip_runtime.h>
#include <hip/hip_fp16.h>

// ---------------------------------------------------------------------------
// GAT 2-layer forward. N=50000 nodes, F=128, E=1.6M random edges (+N implicit
// self loops). L1: H=2,C=64 concat -> relu. L2: H=1,C=16.
//
// Dispatches: memset -> {partition || gemm1} (block-range fused) ->
// bucket_build -> agg1 -> agg2.
//
// Session ledger (R14-R17 measured): aggregation sits on a ~6.6TB/s random-
// request byte wall. agg1 payload = 256B row + 8B alpha per edge = 422MB /
// 65us -> structural floor. Head-split (+5.4us net), packed 64B records
// (+3us: txn count halved but bytes/edge up), wprep2 relocation (+10us),
// bucket-staged chain amortization (2.1x: TLP collapse) ALL regressed ->
// aggregation kept in its R0 (fastest measured) form.
//
// R18 (this): attack the invisible ~145us OUTSIDE agg1. Mechanism: random
// sub-line scatter writes. partition pass-B wrote 1.6M random 4B words
// (one line-touch each, RMW); bucket_build's csr scatter wrote 1.6M random
// 2B. Both now sort into LDS by destination first (block-local exclusive
// scan over buckets / nodes), then stream to global in address order ->
// coalesced runs. Write line-touches 1.6M -> ~0.2M per kernel.
//
// gemm1: fp16 MFMA (mfma_f32_16x16x32_f16), A=x rows, B=w1 rows ([o][i] =
// B^T fed directly), LDS stride-136 fp16, fp32 accumulate, epilogue stages C
// through LDS for coalesced fp16 stores + fused logits.
//
// agg1 fuses: softmax aggregation + relu + bias (h in registers) + gemm2
// (h @ w2^T) + layer-2 logits. Softmax without max-shift (logits bounded,
// fp32 exp safe; ratio identical to reference in exact math). xw fp16.
// ---------------------------------------------------------------------------

#define BSHIFT 7                 // 128 dst nodes per bucket
#define MAXB 512                 // supports N <= 65536
#define CAPMAX 6144              // LDS edge-staging bound (entries)
#define XS 136
#define NBP 320                  // partition blocks (CH=5000 -> 2x20KB LDS)

using f16x8 = __attribute__((ext_vector_type(8))) _Float16;
using f16x4 = __attribute__((ext_vector_type(4))) _Float16;
using f32x4 = __attribute__((ext_vector_type(4))) float;

__device__ __forceinline__ float lrelu(float a) { return fmaxf(a, 0.2f * a); }

// ---------------- fused: partition (blocks 0..NBP-1) + gemm1 (rest) -------

__global__ __launch_bounds__(256) void part_gemm1_kernel(
    const int* __restrict__ src, const int* __restrict__ dst,
    int* __restrict__ bincur, unsigned* __restrict__ binned,
    int E, int B, int CH, int CAP,
    const float* __restrict__ x, const float* __restrict__ w1,
    const float* __restrict__ as1, const float* __restrict__ ad1,
    __half* __restrict__ xw1h, float* __restrict__ asrc1,
    float* __restrict__ adst1, int N) {
  __shared__ __align__(16) char smem[(64 + 128) * XS * 2];  // 52224 B
  int t = threadIdx.x;

  if (blockIdx.x < (unsigned)NBP) {
    // ---- partition: single global pass; LDS-sort by bucket, then
    //      coalesced write-out (R18: was 1.6M random 4B scatter writes) ----
    int* s_h = (int*)smem;                     // per-bucket count
    int* s_base = s_h + MAXB;                  // global reserved base
    int* s_cur = s_base + MAXB;                // scatter cursor (local)
    int* s_lbase = s_cur + MAXB;               // local exclusive scan
    unsigned* s_pack = (unsigned*)(s_lbase + MAXB);  // CH words
    unsigned* s_sorted = s_pack + CH;                // CH words
    int lane = t & 63, wv = t >> 6;
    for (int i = t; i < MAXB; i += 256) s_h[i] = 0;
    __syncthreads();
    int lo = blockIdx.x * CH;
    int cnt = min(CH, E - lo);
    for (int i = t; i < cnt; i += 256) {
      int d = dst[lo + i];
      int s = src[lo + i];
      atomicAdd(&s_h[d >> BSHIFT], 1);
      s_pack[i] = (unsigned)s | ((unsigned)(d & 127) << 16) |
                  ((unsigned)(d >> BSHIFT) << 23);
    }
    __syncthreads();
    // wave-0 exclusive scan over MAXB buckets
    if (wv == 0) {
      int run = 0;
#pragma unroll
      for (int c = 0; c < MAXB / 64; ++c) {
        int idx = c * 64 + lane;
        int v = s_h[idx];
        int incl = v;
#pragma unroll
        for (int off = 1; off < 64; off <<= 1) {
          int u = __shfl_up(incl, off);
          if (lane >= off) incl += u;
        }
        s_lbase[idx] = run + incl - v;
        run += __shfl(incl, 63);
      }
    }
    __syncthreads();
    for (int i = t; i < B; i += 256) {
      int c = s_h[i];
      s_base[i] = c ? (i * CAP + atomicAdd(&bincur[i], c)) : 0;
      s_cur[i] = s_lbase[i];
    }
    __syncthreads();
    for (int i = t; i < cnt; i += 256) {
      unsigned e = s_pack[i];
      int r = atomicAdd(&s_cur[e >> 23], 1);
      s_sorted[r] = e;  // keep bucket bits for pass C
    }
    __syncthreads();
    for (int j = t; j < cnt; j += 256) {
      unsigned e = s_sorted[j];
      int b = e >> 23;
      binned[s_base[b] + (j - s_lbase[b])] = e & 0x7FFFFFu;  // coalesced runs
    }
    return;
  }

  // ---- gemm1: 64-node tile, fp16 MFMA, fused logits ----
  _Float16* lx = (_Float16*)smem;
  _Float16* lw = lx + 64 * XS;
  int n0 = (blockIdx.x - NBP) * 64;

#pragma unroll
  for (int j = 0; j < 8; ++j) {
    int idx = t + 256 * j;
    int nd = idx >> 5, i4 = (idx & 31) * 4;
    int gn = n0 + nd;
    float4 v = (gn < N) ? *(const float4*)&x[(size_t)gn * 128 + i4]
                        : make_float4(0.f, 0.f, 0.f, 0.f);
    f16x4 h;
    h[0] = (_Float16)v.x; h[1] = (_Float16)v.y;
    h[2] = (_Float16)v.z; h[3] = (_Float16)v.w;
    *(f16x4*)&lx[nd * XS + i4] = h;
  }
#pragma unroll
  for (int j = 0; j < 16; ++j) {
    int idx = t + 256 * j;
    int o = idx >> 5, i4 = (idx & 31) * 4;
    float4 v = *(const float4*)&w1[(size_t)o * 128 + i4];
    f16x4 h;
    h[0] = (_Float16)v.x; h[1] = (_Float16)v.y;
    h[2] = (_Float16)v.z; h[3] = (_Float16)v.w;
    *(f16x4*)&lw[o * XS + i4] = h;
  }
  __syncthreads();

  int lane = t & 63, wv = t >> 6;
  int m16 = lane & 15, q = lane >> 4;

  f32x4 acc[8];
#pragma unroll
  for (int i = 0; i < 8; ++i) acc[i] = (f32x4){0.f, 0.f, 0.f, 0.f};

#pragma unroll
  for (int c = 0; c < 4; ++c) {
    f16x8 a = *(const f16x8*)&lx[(16 * wv + m16) * XS + c * 32 + q * 8];
#pragma unroll
    for (int tt = 0; tt < 8; ++tt) {
      f16x8 b = *(const f16x8*)&lw[(tt * 16 + m16) * XS + c * 32 + q * 8];
      acc[tt] = __builtin_amdgcn_mfma_f32_16x16x32_f16(a, b, acc[tt], 0, 0, 0);
    }
  }

  // write C to this wave's own lx rows (wave-private; no barrier needed)
#pragma unroll
  for (int tt = 0; tt < 8; ++tt) {
#pragma unroll
    for (int r = 0; r < 4; ++r) {
      lx[(16 * wv + 4 * q + r) * XS + tt * 16 + m16] = (_Float16)acc[tt][r];
    }
  }

  // logits: lane -> node m16, o-part p = q (32 outputs each)
  {
    float ps = 0.f, pd = 0.f;
    int p = q;
#pragma unroll
    for (int k = 0; k < 4; ++k) {
      f16x8 hv = *(const f16x8*)&lx[(16 * wv + m16) * XS + p * 32 + k * 8];
      float4 s0 = *(const float4*)&as1[p * 32 + k * 8];
      float4 s1 = *(const float4*)&as1[p * 32 + k * 8 + 4];
      float4 d0 = *(const float4*)&ad1[p * 32 + k * 8];
      float4 d1 = *(const float4*)&ad1[p * 32 + k * 8 + 4];
      ps += (float)hv[0] * s0.x + (float)hv[1] * s0.y + (float)hv[2] * s0.z +
            (float)hv[3] * s0.w + (float)hv[4] * s1.x + (float)hv[5] * s1.y +
            (float)hv[6] * s1.z + (float)hv[7] * s1.w;
      pd += (float)hv[0] * d0.x + (float)hv[1] * d0.y + (float)hv[2] * d0.z +
            (float)hv[3] * d0.w + (float)hv[4] * d1.x + (float)hv[5] * d1.y +
            (float)hv[6] * d1.z + (float)hv[7] * d1.w;
    }
    ps += __shfl_xor(ps, 16);
    pd += __shfl_xor(pd, 16);
    int n = n0 + 16 * wv + m16;
    if (n < N && (q == 0 || q == 2)) {
      int hh = q >> 1;
      asrc1[2 * n + hh] = ps;
      adst1[2 * n + hh] = pd;
    }
  }

  // coalesced fp16 stores: 16 rows x 16 uint4 per wave -> 4 per lane
#pragma unroll
  for (int i = 0; i < 4; ++i) {
    int m = q + 4 * i;
    int n = n0 + 16 * wv + m;
    if (n < N) {
      uint4 v = *(const uint4*)&lx[(16 * wv + m) * XS + m16 * 8];
      *(uint4*)&xw1h[(size_t)n * 128 + m16 * 8] = v;
    }
  }
}

// ---------------- bucket_build: LDS-sorted csr, coalesced write-out -------

__global__ __launch_bounds__(256) void bucket_build_kernel(const unsigned* __restrict__ binned,
                                                           const int* __restrict__ bincur,
                                                           int2* __restrict__ nodeseg,
                                                           unsigned short* __restrict__ csr,
                                                           int N, int CAP) {
  __shared__ int s_deg[128];
  __shared__ int s_cur[128];
  __shared__ int s_wsum;
  __shared__ unsigned s_edges[CAPMAX];
  __shared__ unsigned short s_csr[CAPMAX];  // R18: local CSR image
  int b = blockIdx.x;
  int lo = b * CAP, hi = lo + bincur[b];
  int cnt = hi - lo;
  int t = threadIdx.x;
  if (t < 128) s_deg[t] = 0;
  int stg = min(cnt, CAPMAX);
  for (int i = t; i < stg; i += 256) s_edges[i] = binned[lo + i];
  __syncthreads();
  for (int i = t; i < cnt; i += 256) {
    unsigned e = (i < CAPMAX) ? s_edges[i] : binned[lo + i];
    atomicAdd(&s_deg[e >> 16], 1);
  }
  __syncthreads();
  int lane = t & 63, wv = t >> 6;
  int v = (t < 128) ? s_deg[t] : 0;
  int incl = v;
#pragma unroll
  for (int off = 1; off < 64; off <<= 1) {
    int u = __shfl_up(incl, off);
    if (lane >= off) incl += u;
  }
  if (t == 63) s_wsum = incl;  // wave-0 total
  __syncthreads();
  int excl = incl - v + ((wv == 1) ? s_wsum : 0);
  if (t < 128) {
    int node = (b << BSHIFT) + t;
    if (node < N) nodeseg[node] = make_int2(lo + excl, lo + excl + v);
    s_cur[t] = excl;  // LOCAL cursor (R18)
  }
  __syncthreads();
  for (int i = t; i < cnt; i += 256) {
    unsigned e = (i < CAPMAX) ? s_edges[i] : binned[lo + i];
    int p = atomicAdd(&s_cur[e >> 16], 1);  // LDS atomic, local slot
    s_csr[p] = (unsigned short)(e & 0xFFFFu);
  }
  __syncthreads();
  for (int j = t; j < cnt; j += 256) csr[lo + j] = s_csr[j];  // coalesced
}

// ---------------- agg1: aggregation + fused relu/bias/gemm2/logits --------

// wave per dst node. 4 rows x 16 lanes x 16B (8-edge loop, 2 loads in
// flight). Sits on the ~6.6TB/s request wall: 256B row + 8B alpha per edge
// = 422MB/65us. Do NOT restructure (R14-R17: every variant regressed).
__global__ __launch_bounds__(256) void agg1_kernel(const __half* __restrict__ xw1h,
                                                   const float* __restrict__ asrc1,
                                                   const float* __restrict__ adst1,
                                                   const float* __restrict__ b1,
                                                   const float* __restrict__ w2,
                                                   const float* __restrict__ as2,
                                                   const float* __restrict__ ad2,
                                                   const unsigned short* __restrict__ csr,
                                                   const int2* __restrict__ nodeseg,
                                                   __half* __restrict__ xw2h,
                                                   float* __restrict__ asrc2,
                                                   float* __restrict__ adst2, int N) {
  __shared__ int s_off[4][64];    // row byte offset (s * 256)
  __shared__ float2 s_w[4][64];   // exp weights per head
  int lane = threadIdx.x & 63, wv = threadIdx.x >> 6;
  int d = blockIdx.x * 4 + wv;
  if (d >= N) return;
  int c8 = lane & 15;   // channels 8*c8 .. 8*c8+7
  int row = lane >> 4;  // 0..3 edge subgroup
  int head = c8 >> 3;   // head of these channels
  int2 seg = nodeseg[d];
  int e0 = seg.x, e1 = seg.y;
  float2 asv = *(const float2*)&asrc1[2 * d];
  float2 adv = *(const float2*)&adst1[2 * d];
  float wself = __expf(lrelu(head ? (asv.y + adv.y) : (asv.x + adv.x)));

  const char* xb = (const char*)xw1h + 16 * c8;  // channel base

  float a[8];
  float sum = 0.f;
#pragma unroll
  for (int k = 0; k < 8; ++k) a[k] = 0.f;
  if (row == 0) {  // self edge handled once, by row 0
    uint4 r = *(const uint4*)(xb + ((size_t)d << 8));
    const __half2* hp = (const __half2*)&r;
#pragma unroll
    for (int k = 0; k < 4; ++k) {
      float2 v = __half22float2(hp[k]);
      a[2 * k] = wself * v.x;
      a[2 * k + 1] = wself * v.y;
    }
    sum = wself;
  }

  for (int base = e0; base < e1; base += 64) {
    int cnt = min(64, e1 - base);
    if (lane < cnt) {
      int s = (int)csr[base + lane];
      float2 aa = *(const float2*)&asrc1[2 * s];
      s_off[wv][lane] = s << 8;
      float2 w;
      w.x = __expf(lrelu(aa.x + adv.x));
      w.y = __expf(lrelu(aa.y + adv.y));
      s_w[wv][lane] = w;
    }
    // wave-private LDS: same wave wrote it; no barrier needed
    int j = 0;
    for (; j + 7 < cnt; j += 8) {
      int oA = s_off[wv][j + row];
      int oB = s_off[wv][j + 4 + row];
      float wA = ((const float*)&s_w[wv][j + row])[head];
      float wB = ((const float*)&s_w[wv][j + 4 + row])[head];
      uint4 rA = *(const uint4*)(xb + oA);
      uint4 rB = *(const uint4*)(xb + oB);
      const __half2* hA = (const __half2*)&rA;
      const __half2* hB = (const __half2*)&rB;
#pragma unroll
      for (int k = 0; k < 4; ++k) {
        float2 vA = __half22float2(hA[k]);
        float2 vB = __half22float2(hB[k]);
        a[2 * k] += wA * vA.x + wB * vB.x;
        a[2 * k + 1] += wA * vA.y + wB * vB.y;
      }
      sum += wA + wB;
    }
    for (; j < cnt; j += 4) {
      if (row < cnt - j) {
        int oA = s_off[wv][j + row];
        float wA = ((const float*)&s_w[wv][j + row])[head];
        uint4 rA = *(const uint4*)(xb + oA);
        const __half2* hA = (const __half2*)&rA;
#pragma unroll
        for (int k = 0; k < 4; ++k) {
          float2 vA = __half22float2(hA[k]);
          a[2 * k] += wA * vA.x;
          a[2 * k + 1] += wA * vA.y;
        }
        sum += wA;
      }
    }
  }

  // butterfly across the 4 rows -> every lane holds full sums for its c8
#pragma unroll
  for (int k = 0; k < 8; ++k) {
    a[k] += __shfl_xor(a[k], 16);
    a[k] += __shfl_xor(a[k], 32);
  }
  sum += __shfl_xor(sum, 16);
  sum += __shfl_xor(sum, 32);

  // h (relu'd, biased) in registers — every lane holds 8 channels
  float inv = 1.f / (sum + 1e-16f);
  float4 blo = *(const float4*)&b1[8 * c8];
  float4 bhi = *(const float4*)&b1[8 * c8 + 4];
  float h[8];
  h[0] = fmaxf(a[0] * inv + blo.x, 0.f);
  h[1] = fmaxf(a[1] * inv + blo.y, 0.f);
  h[2] = fmaxf(a[2] * inv + blo.z, 0.f);
  h[3] = fmaxf(a[3] * inv + blo.w, 0.f);
  h[4] = fmaxf(a[4] * inv + bhi.x, 0.f);
  h[5] = fmaxf(a[5] * inv + bhi.y, 0.f);
  h[6] = fmaxf(a[6] * inv + bhi.z, 0.f);
  h[7] = fmaxf(a[7] * inv + bhi.w, 0.f);

  // fused gemm2: row r computes xw2 channels r*4..r*4+3 (butterfly over 16)
  float p[4];
#pragma unroll
  for (int cc = 0; cc < 4; ++cc) {
    const float4 wlo = *(const float4*)&w2[(row * 4 + cc) * 128 + 8 * c8];
    const float4 whi = *(const float4*)&w2[(row * 4 + cc) * 128 + 8 * c8 + 4];
    p[cc] = h[0] * wlo.x + h[1] * wlo.y + h[2] * wlo.z + h[3] * wlo.w +
            h[4] * whi.x + h[5] * whi.y + h[6] * whi.z + h[7] * whi.w;
#pragma unroll
    for (int k = 1; k < 16; k <<= 1) p[cc] += __shfl_xor(p[cc], k);
  }
  float qs = 0.f, qd = 0.f;
#pragma unroll
  for (int cc = 0; cc < 4; ++cc) {
    qs += p[cc] * as2[row * 4 + cc];
    qd += p[cc] * ad2[row * 4 + cc];
  }
  qs += __shfl_xor(qs, 16);
  qs += __shfl_xor(qs, 32);
  qd += __shfl_xor(qd, 16);
  qd += __shfl_xor(qd, 32);
  if (lane == 0) {
    asrc2[d] = qs;
    adst2[d] = qd;
  }
  if (c8 == 0) {  // one lane per row stores its 4 channels (8B)
    union {
      __half hh[4];
      uint2 u;
    } pk;
#pragma unroll
    for (int cc = 0; cc < 4; ++cc) pk.hh[cc] = __float2half(p[cc]);
    *(uint2*)&xw2h[(size_t)d * 16 + row * 4] = pk.u;
  }
}

// ---------------- agg2 ----------------

// wave per dst node. 8 rows x 8 lanes x 4B; 16-edge unroll = 2 loads in
// flight. Each lane owns 2 channels (half2).
__global__ __launch_bounds__(256) void agg2_kernel(const __half* __restrict__ xw2h,
                                                   const float* __restrict__ asrc2,
                                                   const float* __restrict__ adst2,
                                                   const float* __restrict__ b2,
                                                   const unsigned short* __restrict__ csr,
                                                   const int2* __restrict__ nodeseg,
                                                   float* __restrict__ out, int N) {
  __shared__ int s_off[4][64];   // row byte offset (s * 32)
  __shared__ float s_w[4][64];
  int lane = threadIdx.x & 63, wv = threadIdx.x >> 6;
  int d = blockIdx.x * 4 + wv;
  if (d >= N) return;
  int c2 = lane & 7;   // channels 2*c2, 2*c2+1
  int row = lane >> 3; // 0..7
  int2 seg = nodeseg[d];
  int e0 = seg.x, e1 = seg.y;
  float advd = adst2[d];
  float wself = __expf(lrelu(asrc2[d] + advd));
  const char* xb = (const char*)xw2h + 4 * c2;

  float a0 = 0.f, a1 = 0.f, sum = 0.f;
  if (row == 0) {
    float2 v = __half22float2(*(const __half2*)(xb + (size_t)d * 32));
    a0 = wself * v.x;
    a1 = wself * v.y;
    sum = wself;
  }
  for (int base = e0; base < e1; base += 64) {
    int cnt = min(64, e1 - base);
    if (lane < cnt) {
      int s = (int)csr[base + lane];
      s_off[wv][lane] = s << 5;
      s_w[wv][lane] = __expf(lrelu(asrc2[s] + advd));
    }
    int j = 0;
    for (; j + 15 < cnt; j += 16) {
      int o0 = s_off[wv][j + row];
      int o1 = s_off[wv][j + 8 + row];
      float w0 = s_w[wv][j + row];
      float w1 = s_w[wv][j + 8 + row];
      float2 v0 = __half22float2(*(const __half2*)(xb + o0));
      float2 v1 = __half22float2(*(const __half2*)(xb + o1));
      a0 += w0 * v0.x + w1 * v1.x;
      a1 += w0 * v0.y + w1 * v1.y;
      sum += w0 + w1;
    }
    for (; j + 7 < cnt; j += 8) {
      int o0 = s_off[wv][j + row];
      float w0 = s_w[wv][j + row];
      float2 v0 = __half22float2(*(const __half2*)(xb + o0));
      a0 += w0 * v0.x;
      a1 += w0 * v0.y;
      sum += w0;
    }
    if (row < cnt - j) {  // tail: rows 0..cnt-j-1 take one edge each
      int o0 = s_off[wv][j + row];
      float w0 = s_w[wv][j + row];
      float2 v0 = __half22float2(*(const __half2*)(xb + o0));
      a0 += w0 * v0.x;
      a1 += w0 * v0.y;
      sum += w0;
    }
  }
#pragma unroll
  for (int k = 8; k < 64; k <<= 1) {
    a0 += __shfl_xor(a0, k);
    a1 += __shfl_xor(a1, k);
    sum += __shfl_xor(sum, k);
  }
  if (lane < 8) {
    float inv = 1.f / (sum + 1e-16f);
    float2 r;
    r.x = a0 * inv + b2[2 * c2];
    r.y = a1 * inv + b2[2 * c2 + 1];
    *(float2*)&out[(size_t)d * 16 + 2 * c2] = r;
  }
}

// ---------------------------------------------------------------------------

extern "C" void kernel_launch(void* const* d_in, const int* in_sizes, int n_in,
                              void* d_out, int out_size, void* d_ws, size_t ws_size,
                              hipStream_t stream) {
  const float* x = (const float*)d_in[0];
  const int* ei = (const int*)d_in[1];
  const float* w1 = (const float*)d_in[2];
  const float* as1 = (const float*)d_in[3];
  const float* ad1 = (const float*)d_in[4];
  const float* b1 = (const float*)d_in[5];
  const float* w2 = (const float*)d_in[6];
  const float* as2 = (const float*)d_in[7];
  const float* ad2 = (const float*)d_in[8];
  const float* b2 = (const float*)d_in[9];
  float* out = (float*)d_out;

  int N = in_sizes[0] / 128;
  int E = in_sizes[1] / 2;
  const int* srcp = ei;
  const int* dstp = ei + E;

  int B = (N + (1 << BSHIFT) - 1) >> BSHIFT;  // 391 buckets (N<=65536 req'd)
  // bucket capacity: mean + 25% slack (+512), rounded to 256 (Poisson ~16sig)
  int mean = (E + B - 1) / B;
  int CAP = (mean + mean / 4 + 512 + 255) & ~255;
  int CH = (E + NBP - 1) / NBP;  // 5000 -> 2x20KB LDS sort buffers
  int GB = (N + 63) / 64;        // gemm1 tiles

  char* p = (char*)d_ws;
  auto alloc = [&](size_t bytes) -> void* {
    void* r = (void*)p;
    p += (bytes + 255) & ~(size_t)255;
    return r;
  };
  __half* xw1h = (__half*)alloc((size_t)N * 128 * 2);
  float* asrc1 = (float*)alloc((size_t)N * 2 * 4);
  float* adst1 = (float*)alloc((size_t)N * 2 * 4);
  __half* xw2h = (__half*)alloc((size_t)N * 16 * 2);
  float* asrc2 = (float*)alloc((size_t)N * 4);
  float* adst2 = (float*)alloc((size_t)N * 4);
  int2* nodeseg = (int2*)alloc((size_t)N * 8);
  unsigned short* csr = (unsigned short*)alloc((size_t)B * CAP * 2);
  unsigned* binned = (unsigned*)alloc((size_t)B * CAP * 4);
  int* bincur = (int*)alloc((size_t)B * 4);

  hipMemsetAsync(bincur, 0, (size_t)B * 4, stream);
  part_gemm1_kernel<<<NBP + GB, 256, 0, stream>>>(srcp, dstp, bincur, binned,
                                                  E, B, CH, CAP,
                                                  x, w1, as1, ad1, xw1h, asrc1, adst1, N);
  bucket_build_kernel<<<B, 256, 0, stream>>>(binned, bincur, nodeseg, csr, N, CAP);
  agg1_kernel<<<(N + 3) / 4, 256, 0, stream>>>(xw1h, asrc1, adst1, b1, w2, as2, ad2,
                                               csr, nodeseg, xw2h, asrc2, adst2, N);
  agg2_kernel<<<(N + 3) / 4, 256, 0, stream>>>(xw2h, asrc2, adst2, b2, csr, nodeseg, out, N);
}